// Round 4
// baseline (655.284 us; speedup 1.0000x reference)
//
#include <hip/hip_runtime.h>

#define N_NODES 10000
#define N_RELS  50
#define R_AUG   101
#define D       128
#define N_EDGES 320000
#define E_AUG   650000   /* 2*N_EDGES + N_NODES */
#define N_BATCH 65536

#define NP      (R_AUG * N_NODES)            /* 1,010,000 (rel,dst) bins */
#define NPB4    ((NP + 1023) / 1024)         /* 987 scan blocks (4 elem/thread) */
#define SCAT_BLOCKS ((E_AUG + 255) / 256)    /* 2540 */

/* fused prep kernel block ranges: hist FIRST (latency-bound atomics start at t=0) */
#define HIST_BLOCKS  2540                    /* ceil(E_AUG/256) */
#define TW_BLOCKS    808                     /* 2*2*(2*R_AUG) */
#define PREPX_BLOCKS 1250                    /* N_NODES*D/(256*4) */

/* fused layer geometry: 64 dsts x 1/8 of rels per block */
#define DSPAN   64
#define NDBLK   ((N_NODES + DSPAN - 1) / DSPAN)   /* 157 */
#define RSPLIT  8
#define FUSE_BLOCKS (NDBLK * RSPLIT)              /* 1256 */
#define NRMAX   13                                /* max rels per group */

typedef short bf16x8 __attribute__((ext_vector_type(8)));
typedef float f32x4  __attribute__((ext_vector_type(4)));

__device__ __forceinline__ unsigned short f2bf(float f) {
    union { float f; unsigned int u; } v; v.f = f;
    unsigned int r = (v.u + 0x7FFFu + ((v.u >> 16) & 1u)) >> 16;
    return (unsigned short)r;
}
__device__ __forceinline__ float bf2f(unsigned short h) {
    union { unsigned int u; float f; } v; v.u = ((unsigned int)h) << 16;
    return v.f;
}

__device__ __forceinline__ void decode_edge(const int* __restrict__ g, int e,
                                            int& src, int& rel, int& dst) {
    if (e < N_EDGES)            { src = g[3*e];     rel = g[3*e+1];          dst = g[3*e+2]; }
    else if (e < 2*N_EDGES)     { int b = e - N_EDGES;
                                  src = g[3*b+2];   rel = g[3*b+1] + N_RELS; dst = g[3*b];   }
    else                        { int n = e - 2*N_EDGES; src = n; dst = n; rel = 2*N_RELS;   }
}

// ---------------- fused prep: deg_hist | transpose_w | x->bf16 ----------------

__global__ __launch_bounds__(256) void prep_all(const float* __restrict__ x,
                                                unsigned short* __restrict__ xb,
                                                const float* __restrict__ W1,
                                                const float* __restrict__ W2,
                                                unsigned short* __restrict__ W1t,
                                                unsigned short* __restrict__ W2t,
                                                const int* __restrict__ g,
                                                int* __restrict__ deg) {
    __shared__ float tile[64][65];
    int b = blockIdx.x, t = threadIdx.x;
    if (b < HIST_BLOCKS) {
        int e = b * 256 + t;
        if (e < E_AUG) {
            int src, rel, dst;
            decode_edge(g, e, src, rel, dst);
            (void)src;
            atomicAdd(&deg[rel * N_NODES + dst], 1);
        }
    } else if (b < HIST_BLOCKS + TW_BLOCKS) {
        int q = b - HIST_BLOCKS;
        int d0 = (q & 1) * 64, o0 = ((q >> 1) & 1) * 64;
        int z = q >> 2;                                  /* 0..201 */
        const float* W = (z < R_AUG) ? W1 : W2;
        unsigned short* Wt = (z < R_AUG) ? W1t : W2t;
        int r = (z < R_AUG) ? z : (z - R_AUG);
        int tx = t & 63, ty = t >> 6;
        #pragma unroll
        for (int i = ty; i < 64; i += 4)
            tile[i][tx] = W[((size_t)r * D + (d0 + i)) * D + (o0 + tx)];
        __syncthreads();
        #pragma unroll
        for (int i = ty; i < 64; i += 4)
            Wt[((size_t)r * D + (o0 + i)) * D + (d0 + tx)] = f2bf(tile[tx][i]);
    } else {
        int i = (b - HIST_BLOCKS - TW_BLOCKS) * 1024 + t * 4;  // covers N_NODES*D exactly
        float4 xv = *(const float4*)(x + i);
        ushort4 o;
        o.x = f2bf(xv.x); o.y = f2bf(xv.y); o.z = f2bf(xv.z); o.w = f2bf(xv.w);
        *(ushort4*)(xb + i) = o;
    }
}

// ---- scan A: per-block exclusive scan of deg[NP] (4 elem/thread) ----

__global__ __launch_bounds__(256) void scan_a(const int* __restrict__ deg,
                                              int* __restrict__ binoff,
                                              int* __restrict__ ppart) {
    __shared__ int wsum[4];
    int t = threadIdx.x, lane = t & 63, w = t >> 6;
    int i0 = blockIdx.x * 1024 + t * 4;
    int4 d = {0, 0, 0, 0};
    if (i0 < NP) d = *(const int4*)(deg + i0);          // NP % 4 == 0, safe
    int e1 = d.x, e2 = e1 + d.y, e3 = e2 + d.z, v = e3 + d.w;
    int incl = v;
    #pragma unroll
    for (int off = 1; off < 64; off <<= 1) {
        int u = __shfl_up(incl, off, 64);
        if (lane >= off) incl += u;
    }
    if (lane == 63) wsum[w] = incl;
    __syncthreads();
    int woff = 0;
    for (int k = 0; k < w; k++) woff += wsum[k];
    int texcl = woff + incl - v;
    if (i0 < NP) {
        int4 o = {texcl, texcl + e1, texcl + e2, texcl + e3};
        *(int4*)(binoff + i0) = o;
    }
    if (t == 255) ppart[blockIdx.x] = woff + incl;
}

// ---- scan B: single block serial-carry over ppart[NPB4]; binoff[NP] = total ----

__global__ __launch_bounds__(256) void scan_b(int* __restrict__ ppart,
                                              int* __restrict__ binoff) {
    __shared__ int wsum[4];
    int t = threadIdx.x, lane = t & 63, w = t >> 6;
    int carry = 0;
    for (int base = 0; base < NPB4; base += 256) {
        int i = base + t;
        int v = (i < NPB4) ? ppart[i] : 0;
        int incl = v;
        #pragma unroll
        for (int off = 1; off < 64; off <<= 1) {
            int u = __shfl_up(incl, off, 64);
            if (lane >= off) incl += u;
        }
        if (lane == 63) wsum[w] = incl;
        __syncthreads();
        int woff = 0;
        for (int k = 0; k < w; k++) woff += wsum[k];
        if (i < NPB4) ppart[i] = carry + woff + incl - v;
        carry += wsum[0] + wsum[1] + wsum[2] + wsum[3];
        __syncthreads();
    }
    if (t == 0) binoff[NP] = carry;
}

// ---- scan C: add block offsets; init cursor = binoff ----

__global__ __launch_bounds__(256) void scan_c(int* __restrict__ binoff,
                                              const int* __restrict__ ppart,
                                              int* __restrict__ cursor) {
    int i0 = blockIdx.x * 1024 + threadIdx.x * 4;
    if (i0 >= NP) return;
    int pp = ppart[blockIdx.x];
    int4 sv = *(int4*)(binoff + i0);
    sv.x += pp; sv.y += pp; sv.z += pp; sv.w += pp;
    *(int4*)(binoff + i0) = sv;
    *(int4*)(cursor + i0) = sv;
}

// ---- edge scatter: sorted by (rel, dst) bin; record = src (ushort) ----

__global__ __launch_bounds__(256) void scatter_edges(const int* __restrict__ g,
                                                     int* __restrict__ cursor,
                                                     unsigned short* __restrict__ esrc) {
    int e = blockIdx.x * 256 + threadIdx.x;
    if (e >= E_AUG) return;
    int src, rel, dst;
    decode_edge(g, e, src, rel, dst);
    int pos = atomicAdd(&cursor[rel * N_NODES + dst], 1);
    esrc[pos] = (unsigned short)src;
}

// ---------------- fused layer v3.1: chunked two-stage (agg | mfma) ----------------
// Prologue: build 16-row-aligned compact bin list (per-rel padded) in LDS.
//   entry: .x = edge base in esrc; .y = (ri<<26)|(dloc<<20)|deg  (deg=0 => pad)
// Chunk loop (128 rows per chunk):
//   stage A: 16 streams x 8 rows; batched entry/esrc/gather issue; deg==1 = row copy;
//            pad rows zeroed.
//   stage B: 8 single-rel MFMA tiles per wave (wave owns 32 output cols).
//            *** W rel MUST be tile-uniform: ri0 from the tile's FIRST entry ***
//            (first entry of a tile is always a real bin: segments are 16-aligned
//            and padded-16 < cnt). Per-lane ri from pad entries corrupts the shared
//            A-operand -- that was v3's correctness bug.
// Swizzles: aggbuf/hblk byte ^ ((row&7)<<4)  (2-way max = free, m136).

__global__ __launch_bounds__(256, 2) void fused_layer(const unsigned short* __restrict__ xb,
                                                      const unsigned short* __restrict__ Wt,
                                                      const int* __restrict__ binoff,
                                                      const unsigned short* __restrict__ esrc,
                                                      float* __restrict__ hpart) {
    __shared__ __align__(16) char aggbuf[128 * 256];    // 32 KB bf16 rows
    __shared__ __align__(16) char hblk[DSPAN * 512];    // 32 KB f32 accum
    __shared__ uint2 binlist[NRMAX * DSPAN];            // 6656 B
    __shared__ int pcarr[NRMAX];
    __shared__ int segb[NRMAX + 1];

    int b = blockIdx.x;
    int rg = b / NDBLK;
    int dblk = b - rg * NDBLK;
    int dst0 = dblk * DSPAN;
    int r0 = (rg * R_AUG) / RSPLIT;
    int r1 = ((rg + 1) * R_AUG) / RSPLIT;
    int NR = r1 - r0;                                   /* 12 or 13 */

    int t = threadIdx.x, w = t >> 6, lane = t & 63;
    int lr = lane & 15, lq = lane >> 4;
    int no = w * 32;
    int prow = ((lr >> 2) << 3) + (lr & 3);

    // ---------- prologue step 1: per-rel degree + padded counts ----------
    int i1 = dst0 + lane;     if (i1 > N_NODES) i1 = N_NODES;
    int i2 = dst0 + lane + 1; if (i2 > N_NODES) i2 = N_NODES;
    int B0[4], DG[4];
    #pragma unroll
    for (int p = 0; p < 4; p++) {
        int ri = w + 4 * p;
        B0[p] = 0; DG[p] = 0;
        if (ri < NR) {
            int r = r0 + ri;
            B0[p] = binoff[r * N_NODES + i1];
            DG[p] = binoff[r * N_NODES + i2] - B0[p];
        }
        unsigned long long mask = __ballot(DG[p] > 0);
        if (ri < NR && lane == 0) pcarr[ri] = (__popcll(mask) + 15) & ~15;
    }
    __syncthreads();

    // ---------- prologue step 2: prefix over rel segments ----------
    if (w == 0) {
        int v = (lane < NR) ? pcarr[lane] : 0;
        int incl = v;
        #pragma unroll
        for (int off = 1; off < 64; off <<= 1) {
            int u = __shfl_up(incl, off, 64);
            if (lane >= off) incl += u;
        }
        if (lane < NR) segb[lane] = incl - v;
        if (lane == NR - 1) segb[NR] = incl;
    }
    __syncthreads();
    int nbtot = segb[NR];                               /* multiple of 16 */

    // ---------- prologue step 3: write entries + pads; zero hblk ----------
    #pragma unroll
    for (int p = 0; p < 4; p++) {
        int ri = w + 4 * p;
        unsigned long long mask = __ballot(DG[p] > 0);
        if (ri < NR) {
            int cnt = __popcll(mask);
            int pos = __popcll(mask & ((1ull << lane) - 1ull));
            int sb = segb[ri];
            if (DG[p] > 0) {
                uint2 e;
                e.x = (unsigned)B0[p];
                e.y = ((unsigned)ri << 26) | ((unsigned)lane << 20) | (unsigned)DG[p];
                binlist[sb + pos] = e;
            }
            int padded = pcarr[ri];
            if (lane >= cnt && lane < padded) {
                uint2 z = {0u, 0u};
                binlist[sb + lane] = z;
            }
        }
    }
    for (int i = t * 16; i < DSPAN * 512; i += 4096) {
        float4 z = {0.f, 0.f, 0.f, 0.f};
        *(float4*)(hblk + i) = z;
    }
    __syncthreads();

    // ---------- chunk loop ----------
    int s = (w << 2) | lq;          /* stream 0..15 */
    int sl = lane & 15;             /* lane within stream */
    int nchunks = (nbtot + 127) >> 7;
    for (int c = 0; c < nchunks; c++) {
        int cbase = c << 7;
        int nrows = nbtot - cbase; if (nrows > 128) nrows = 128;

        // ===== stage A: aggregate 8 rows per stream, batched issue =====
        uint2 ent[8];
        #pragma unroll
        for (int j = 0; j < 8; j++) {
            int row = (j << 4) + s;
            uint2 e = {0u, 0u};
            if (row < nrows) e = binlist[cbase + row];
            ent[j] = e;
        }
        int src0[8];
        #pragma unroll
        for (int j = 0; j < 8; j++)
            src0[j] = (ent[j].y & 0xFFFFFu) ? (int)esrc[ent[j].x] : 0;
        uint4 gat[8];
        #pragma unroll
        for (int j = 0; j < 8; j++)
            if (ent[j].y & 0xFFFFFu)
                gat[j] = *(const uint4*)(xb + ((size_t)src0[j] << 7) + (sl << 3));
        #pragma unroll
        for (int j = 0; j < 8; j++) {
            unsigned dg = ent[j].y & 0xFFFFFu;
            int row = (j << 4) + s;
            char* dp = aggbuf + ((row * 256 + sl * 16) ^ ((row & 7) << 4));
            if (!dg) {                                   // pad row (or beyond nrows)
                if (row < nrows) { uint4 z = {0u,0u,0u,0u}; *(uint4*)dp = z; }
                continue;
            }
            if (dg == 1) { *(uint4*)dp = gat[j]; continue; }
            float a0 = bf2f((unsigned short)(gat[j].x & 0xFFFFu));
            float a1 = bf2f((unsigned short)(gat[j].x >> 16));
            float a2 = bf2f((unsigned short)(gat[j].y & 0xFFFFu));
            float a3 = bf2f((unsigned short)(gat[j].y >> 16));
            float a4 = bf2f((unsigned short)(gat[j].z & 0xFFFFu));
            float a5 = bf2f((unsigned short)(gat[j].z >> 16));
            float a6 = bf2f((unsigned short)(gat[j].w & 0xFFFFu));
            float a7 = bf2f((unsigned short)(gat[j].w >> 16));
            for (unsigned k = 1; k < dg; k++) {
                int sk = esrc[ent[j].x + k];
                uint4 g2 = *(const uint4*)(xb + ((size_t)sk << 7) + (sl << 3));
                a0 += bf2f((unsigned short)(g2.x & 0xFFFFu));
                a1 += bf2f((unsigned short)(g2.x >> 16));
                a2 += bf2f((unsigned short)(g2.y & 0xFFFFu));
                a3 += bf2f((unsigned short)(g2.y >> 16));
                a4 += bf2f((unsigned short)(g2.z & 0xFFFFu));
                a5 += bf2f((unsigned short)(g2.z >> 16));
                a6 += bf2f((unsigned short)(g2.w & 0xFFFFu));
                a7 += bf2f((unsigned short)(g2.w >> 16));
            }
            float scl = 1.0f / (float)dg;
            uint4 o;
            o.x = (unsigned)f2bf(a0 * scl) | ((unsigned)f2bf(a1 * scl) << 16);
            o.y = (unsigned)f2bf(a2 * scl) | ((unsigned)f2bf(a3 * scl) << 16);
            o.z = (unsigned)f2bf(a4 * scl) | ((unsigned)f2bf(a5 * scl) << 16);
            o.w = (unsigned)f2bf(a6 * scl) | ((unsigned)f2bf(a7 * scl) << 16);
            *(uint4*)dp = o;
        }
        __syncthreads();

        // ===== stage B: MFMA tiles (single-rel by 16-alignment) =====
        int ntiles = nrows >> 4;
        for (int tt = 0; tt < ntiles; tt++) {
            int tb = cbase + (tt << 4);
            uint2 e = binlist[tb + lr];
            unsigned ri0 = binlist[tb].y >> 26;          // tile-uniform rel (first entry real)
            int dloc = (e.y >> 20) & 63;
            unsigned dg = e.y & 0xFFFFFu;
            const unsigned short* Wr = Wt + ((size_t)(r0 + (int)ri0) << 14);
            bf16x8 w0[4], w1[4];
            #pragma unroll
            for (int ks = 0; ks < 4; ks++) {
                size_t kb = (size_t)(ks << 5) + (lq << 3);
                w0[ks] = *(const bf16x8*)(Wr + (size_t)(no + prow) * D + kb);
                w1[ks] = *(const bf16x8*)(Wr + (size_t)(no + prow + 4) * D + kb);
            }
            f32x4 c0 = {}, c1 = {};
            int rloc = (tt << 4) + lr;
            #pragma unroll
            for (int ks = 0; ks < 4; ks++) {
                bf16x8 a = *(const bf16x8*)(aggbuf +
                              ((rloc * 256 + (ks << 6) + (lq << 4)) ^ ((rloc & 7) << 4)));
                c0 = __builtin_amdgcn_mfma_f32_16x16x32_bf16(w0[ks], a, c0, 0, 0, 0);
                c1 = __builtin_amdgcn_mfma_f32_16x16x32_bf16(w1[ks], a, c1, 0, 0, 0);
            }
            if (dg) {
                int cb = (no + lq * 8) * 4;
                int sw = (dloc & 7) << 4;
                char* hp0 = hblk + ((dloc * 512 + cb) ^ sw);
                char* hp1 = hblk + ((dloc * 512 + cb + 16) ^ sw);
                float4 h0 = *(float4*)hp0;
                h0.x += c0[0]; h0.y += c0[1]; h0.z += c0[2]; h0.w += c0[3];
                *(float4*)hp0 = h0;
                float4 h1 = *(float4*)hp1;
                h1.x += c1[0]; h1.y += c1[1]; h1.z += c1[2]; h1.w += c1[3];
                *(float4*)hp1 = h1;
            }
        }
        __syncthreads();
    }

    // ---------- writeback hblk -> hpart[rg] ----------
    {
        int row = t >> 2, seg = t & 3;
        int dst = dst0 + row;
        if (dst < N_NODES) {
            float* outp = hpart + ((size_t)rg * N_NODES + dst) * D + seg * 32;
            int sw = (row & 7) << 4;
            #pragma unroll
            for (int q = 0; q < 8; q++) {
                float4 v = *(float4*)(hblk + ((row * 512 + seg * 128 + q * 16) ^ sw));
                *(float4*)(outp + q * 4) = v;
            }
        }
    }
}

// ---------------- finish: h = act(sum_s hpart[s] + bias) ----------------

__global__ __launch_bounds__(256) void finish(const float* __restrict__ hpart,
                                              const float* __restrict__ bias,
                                              float* __restrict__ hf,
                                              unsigned short* __restrict__ hb,
                                              int dorelu) {
    int i0 = (blockIdx.x * 256 + threadIdx.x) * 8;      // grid 625 covers N_NODES*D exactly
    int c0 = i0 & 127;
    float4 b0 = *(const float4*)(bias + c0), b1 = *(const float4*)(bias + c0 + 4);
    float v0 = b0.x, v1 = b0.y, v2 = b0.z, v3 = b0.w;
    float v4 = b1.x, v5 = b1.y, v6 = b1.z, v7 = b1.w;
    #pragma unroll
    for (int s = 0; s < RSPLIT; s++) {
        const float* p = hpart + (size_t)s * N_NODES * D + i0;
        float4 x0 = *(const float4*)p, x1 = *(const float4*)(p + 4);
        v0 += x0.x; v1 += x0.y; v2 += x0.z; v3 += x0.w;
        v4 += x1.x; v5 += x1.y; v6 += x1.z; v7 += x1.w;
    }
    if (dorelu) {
        uint4 p;
        p.x = (unsigned)f2bf(fmaxf(v0, 0.f)) | ((unsigned)f2bf(fmaxf(v1, 0.f)) << 16);
        p.y = (unsigned)f2bf(fmaxf(v2, 0.f)) | ((unsigned)f2bf(fmaxf(v3, 0.f)) << 16);
        p.z = (unsigned)f2bf(fmaxf(v4, 0.f)) | ((unsigned)f2bf(fmaxf(v5, 0.f)) << 16);
        p.w = (unsigned)f2bf(fmaxf(v6, 0.f)) | ((unsigned)f2bf(fmaxf(v7, 0.f)) << 16);
        *(uint4*)(hb + i0) = p;
    } else {
        float4 o0 = {v0, v1, v2, v3};
        float4 o1 = {v4, v5, v6, v7};
        *(float4*)(hf + i0) = o0;
        *(float4*)(hf + i0 + 4) = o1;
    }
}

// ---------------- scoring: 4 items/wave (16 lanes x 2 float4 each) ----------------

__global__ __launch_bounds__(256) void score_kernel(const int* __restrict__ batch,
                                                    const float* __restrict__ h2,
                                                    const float* __restrict__ rels,
                                                    float* __restrict__ out) {
    int t = threadIdx.x;
    int wv = t >> 6, q = (t & 63) >> 4, sl = t & 15;
    int i = blockIdx.x * 16 + wv * 4 + q;     // grid 4096 covers 65536 exactly
    int bs = batch[3*i], bp = batch[3*i+1], bo = batch[3*i+2];
    const float* sp = h2   + (size_t)bs * D + sl * 8;
    const float* pp = rels + (size_t)bp * D + sl * 8;
    const float* op = h2   + (size_t)bo * D + sl * 8;
    float4 s0 = *(const float4*)sp,      s1 = *(const float4*)(sp + 4);
    float4 p0 = *(const float4*)pp,      p1 = *(const float4*)(pp + 4);
    float4 o0 = *(const float4*)op,      o1 = *(const float4*)(op + 4);
    float v = s0.x * p0.x * o0.x + s0.y * p0.y * o0.y + s0.z * p0.z * o0.z + s0.w * p0.w * o0.w
            + s1.x * p1.x * o1.x + s1.y * p1.y * o1.y + s1.z * p1.z * o1.z + s1.w * p1.w * o1.w;
    #pragma unroll
    for (int off = 8; off > 0; off >>= 1) v += __shfl_down(v, off, 16);
    if (sl == 0) out[i] = v;
}

// ---------------- host ----------------

extern "C" void kernel_launch(void* const* d_in, const int* in_sizes, int n_in,
                              void* d_out, int out_size, void* d_ws, size_t ws_size,
                              hipStream_t stream) {
    const int*   graph = (const int*)  d_in[0];
    const int*   batch = (const int*)  d_in[1];
    const float* emb   = (const float*)d_in[2];
    const float* W1    = (const float*)d_in[3];
    const float* b1    = (const float*)d_in[4];
    const float* W2    = (const float*)d_in[5];
    const float* b2    = (const float*)d_in[6];
    const float* rels  = (const float*)d_in[7];
    float* out = (float*)d_out;

    char* base = (char*)d_ws;
    size_t off = 0;
    auto take = [&](size_t bytes) -> char* {
        char* q = base + off;
        off += (bytes + 255) & ~(size_t)255;
        return q;
    };
    int*            deg     = (int*)           take((size_t)NP * 4);
    int*            binoff  = (int*)           take((size_t)(NP + 1) * 4);
    int*            cursor  = (int*)           take((size_t)NP * 4);
    int*            ppart   = (int*)           take((size_t)NPB4 * 4);
    unsigned short* esrc    = (unsigned short*)take((size_t)E_AUG * 2);
    unsigned short* xb      = (unsigned short*)take((size_t)N_NODES * D * 2);
    unsigned short* h1b     = (unsigned short*)take((size_t)N_NODES * D * 2);
    float*          h2      = (float*)         take((size_t)N_NODES * D * 4);
    unsigned short* W1t     = (unsigned short*)take((size_t)R_AUG * D * D * 2);
    unsigned short* W2t     = (unsigned short*)take((size_t)R_AUG * D * D * 2);
    float*          hpart   = (float*)         take((size_t)RSPLIT * N_NODES * D * 4);

    hipMemsetAsync(deg, 0, (size_t)NP * 4, stream);
    prep_all<<<dim3(HIST_BLOCKS + TW_BLOCKS + PREPX_BLOCKS), 256, 0, stream>>>(
        emb, xb, W1, W2, W1t, W2t, graph, deg);
    scan_a<<<dim3(NPB4), 256, 0, stream>>>(deg, binoff, ppart);
    scan_b<<<dim3(1), 256, 0, stream>>>(ppart, binoff);
    scan_c<<<dim3(NPB4), 256, 0, stream>>>(binoff, ppart, cursor);
    scatter_edges<<<dim3(SCAT_BLOCKS), 256, 0, stream>>>(graph, cursor, esrc);

    fused_layer<<<dim3(FUSE_BLOCKS), 256, 0, stream>>>(xb, W1t, binoff, esrc, hpart);
    finish<<<dim3(625), 256, 0, stream>>>(hpart, b1, (float*)0, h1b, 1);
    fused_layer<<<dim3(FUSE_BLOCKS), 256, 0, stream>>>(h1b, W2t, binoff, esrc, hpart);
    finish<<<dim3(625), 256, 0, stream>>>(hpart, b2, h2, (unsigned short*)0, 0);
    score_kernel<<<dim3(N_BATCH / 16), 256, 0, stream>>>(batch, h2, rels, out);
}

// Round 6
// 634.867 us; speedup vs baseline: 1.0322x; 1.0322x over previous
//
#include <hip/hip_runtime.h>

#define N_NODES 10000
#define N_RELS  50
#define R_AUG   101
#define D       128
#define N_EDGES 320000
#define E_AUG   650000   /* 2*N_EDGES + N_NODES */
#define N_BATCH 65536

#define NP      (R_AUG * N_NODES)            /* 1,010,000 (rel,dst) bins */
#define NPB4    ((NP + 1023) / 1024)         /* 987 scan blocks (4 elem/thread) */
#define SCAT_BLOCKS ((E_AUG + 255) / 256)    /* 2540 */

/* fused prep kernel block ranges: hist FIRST (latency-bound atomics start at t=0) */
#define HIST_BLOCKS  2540                    /* ceil(E_AUG/256) */
#define TW_BLOCKS    808                     /* 2*2*(2*R_AUG) */
#define PREPX_BLOCKS 1250                    /* N_NODES*D/(256*4) */

/* fused layer geometry: 64 dsts x 1/8 of rels per block */
#define DSPAN   64
#define NDBLK   ((N_NODES + DSPAN - 1) / DSPAN)   /* 157 */
#define RSPLIT  8
#define FUSE_BLOCKS (NDBLK * RSPLIT)              /* 1256 */
#define NRMAX   13                                /* max rels per group */
#define BLMAX   896                               /* binlist cap: ceil(13*64/128)*128 */

typedef short bf16x8 __attribute__((ext_vector_type(8)));
typedef float f32x4  __attribute__((ext_vector_type(4)));

__device__ __forceinline__ unsigned short f2bf(float f) {
    union { float f; unsigned int u; } v; v.f = f;
    unsigned int r = (v.u + 0x7FFFu + ((v.u >> 16) & 1u)) >> 16;
    return (unsigned short)r;
}
__device__ __forceinline__ float bf2f(unsigned short h) {
    union { unsigned int u; float f; } v; v.u = ((unsigned int)h) << 16;
    return v.f;
}

__device__ __forceinline__ void decode_edge(const int* __restrict__ g, int e,
                                            int& src, int& rel, int& dst) {
    if (e < N_EDGES)            { src = g[3*e];     rel = g[3*e+1];          dst = g[3*e+2]; }
    else if (e < 2*N_EDGES)     { int b = e - N_EDGES;
                                  src = g[3*b+2];   rel = g[3*b+1] + N_RELS; dst = g[3*b];   }
    else                        { int n = e - 2*N_EDGES; src = n; dst = n; rel = 2*N_RELS;   }
}

// ---------------- fused prep: deg_hist | transpose_w | x->bf16 ----------------

__global__ __launch_bounds__(256) void prep_all(const float* __restrict__ x,
                                                unsigned short* __restrict__ xb,
                                                const float* __restrict__ W1,
                                                const float* __restrict__ W2,
                                                unsigned short* __restrict__ W1t,
                                                unsigned short* __restrict__ W2t,
                                                const int* __restrict__ g,
                                                int* __restrict__ deg) {
    __shared__ float tile[64][65];
    int b = blockIdx.x, t = threadIdx.x;
    if (b < HIST_BLOCKS) {
        int e = b * 256 + t;
        if (e < E_AUG) {
            int src, rel, dst;
            decode_edge(g, e, src, rel, dst);
            (void)src;
            atomicAdd(&deg[rel * N_NODES + dst], 1);
        }
    } else if (b < HIST_BLOCKS + TW_BLOCKS) {
        int q = b - HIST_BLOCKS;
        int d0 = (q & 1) * 64, o0 = ((q >> 1) & 1) * 64;
        int z = q >> 2;                                  /* 0..201 */
        const float* W = (z < R_AUG) ? W1 : W2;
        unsigned short* Wt = (z < R_AUG) ? W1t : W2t;
        int r = (z < R_AUG) ? z : (z - R_AUG);
        int tx = t & 63, ty = t >> 6;
        #pragma unroll
        for (int i = ty; i < 64; i += 4)
            tile[i][tx] = W[((size_t)r * D + (d0 + i)) * D + (o0 + tx)];
        __syncthreads();
        #pragma unroll
        for (int i = ty; i < 64; i += 4)
            Wt[((size_t)r * D + (o0 + i)) * D + (d0 + tx)] = f2bf(tile[tx][i]);
    } else {
        int i = (b - HIST_BLOCKS - TW_BLOCKS) * 1024 + t * 4;  // covers N_NODES*D exactly
        float4 xv = *(const float4*)(x + i);
        ushort4 o;
        o.x = f2bf(xv.x); o.y = f2bf(xv.y); o.z = f2bf(xv.z); o.w = f2bf(xv.w);
        *(ushort4*)(xb + i) = o;
    }
}

// ---- scan A: per-block exclusive scan of deg[NP] (4 elem/thread) ----

__global__ __launch_bounds__(256) void scan_a(const int* __restrict__ deg,
                                              int* __restrict__ binoff,
                                              int* __restrict__ ppart) {
    __shared__ int wsum[4];
    int t = threadIdx.x, lane = t & 63, w = t >> 6;
    int i0 = blockIdx.x * 1024 + t * 4;
    int4 d = {0, 0, 0, 0};
    if (i0 < NP) d = *(const int4*)(deg + i0);          // NP % 4 == 0, safe
    int e1 = d.x, e2 = e1 + d.y, e3 = e2 + d.z, v = e3 + d.w;
    int incl = v;
    #pragma unroll
    for (int off = 1; off < 64; off <<= 1) {
        int u = __shfl_up(incl, off, 64);
        if (lane >= off) incl += u;
    }
    if (lane == 63) wsum[w] = incl;
    __syncthreads();
    int woff = 0;
    for (int k = 0; k < w; k++) woff += wsum[k];
    int texcl = woff + incl - v;
    if (i0 < NP) {
        int4 o = {texcl, texcl + e1, texcl + e2, texcl + e3};
        *(int4*)(binoff + i0) = o;
    }
    if (t == 255) ppart[blockIdx.x] = woff + incl;
}

// ---- scan B: single block serial-carry over ppart[NPB4]; binoff[NP] = total ----

__global__ __launch_bounds__(256) void scan_b(int* __restrict__ ppart,
                                              int* __restrict__ binoff) {
    __shared__ int wsum[4];
    int t = threadIdx.x, lane = t & 63, w = t >> 6;
    int carry = 0;
    for (int base = 0; base < NPB4; base += 256) {
        int i = base + t;
        int v = (i < NPB4) ? ppart[i] : 0;
        int incl = v;
        #pragma unroll
        for (int off = 1; off < 64; off <<= 1) {
            int u = __shfl_up(incl, off, 64);
            if (lane >= off) incl += u;
        }
        if (lane == 63) wsum[w] = incl;
        __syncthreads();
        int woff = 0;
        for (int k = 0; k < w; k++) woff += wsum[k];
        if (i < NPB4) ppart[i] = carry + woff + incl - v;
        carry += wsum[0] + wsum[1] + wsum[2] + wsum[3];
        __syncthreads();
    }
    if (t == 0) binoff[NP] = carry;
}

// ---- scan C: add block offsets; init cursor = binoff ----

__global__ __launch_bounds__(256) void scan_c(int* __restrict__ binoff,
                                              const int* __restrict__ ppart,
                                              int* __restrict__ cursor) {
    int i0 = blockIdx.x * 1024 + threadIdx.x * 4;
    if (i0 >= NP) return;
    int pp = ppart[blockIdx.x];
    int4 sv = *(int4*)(binoff + i0);
    sv.x += pp; sv.y += pp; sv.z += pp; sv.w += pp;
    *(int4*)(binoff + i0) = sv;
    *(int4*)(cursor + i0) = sv;
}

// ---- edge scatter: sorted by (rel, dst) bin; record = src (ushort) ----

__global__ __launch_bounds__(256) void scatter_edges(const int* __restrict__ g,
                                                     int* __restrict__ cursor,
                                                     unsigned short* __restrict__ esrc) {
    int e = blockIdx.x * 256 + threadIdx.x;
    if (e >= E_AUG) return;
    int src, rel, dst;
    decode_edge(g, e, src, rel, dst);
    int pos = atomicAdd(&cursor[rel * N_NODES + dst], 1);
    esrc[pos] = (unsigned short)src;
}

// ---------------- fused layer v4.1: flat-issue agg + W-pipelined mfma ----------------
// binlist padded to a multiple of 128 rows => every chunk has exactly 8 tiles
// => compile-time-unrolled loops everywhere.
//   entry: .x = edge base in esrc; .y = (ri<<26)|(dloc<<20)|deg  (deg=0 => pad)
// stage A: per stream 2 groups of 4 rows; esrc k=0..2 prefetched with CLAMPED
//   branch-free addresses; all gathers issued flat; only deg>=4 (~0.3%) serial.
// stage B: 8 tiles, W fragments double-buffered (prefetch t+1 during MFMA t).
//   W rel is tile-uniform (first entry of a tile is always real except pure-pad
//   tiles, where ri=0 is a valid, unused load).
// Swizzles: aggbuf/hblk byte ^ ((row&7)<<4)  (2-way max = free, m136).
// launch_bounds (256,2): LDS (71.5 KB) caps residency at 2 blocks/CU anyway;
// a tighter bound would only force VGPR<=128 and risk spilling the W dbuf.

__global__ __launch_bounds__(256, 2) void fused_layer(const unsigned short* __restrict__ xb,
                                                      const unsigned short* __restrict__ Wt,
                                                      const int* __restrict__ binoff,
                                                      const unsigned short* __restrict__ esrc,
                                                      float* __restrict__ hpart) {
    __shared__ __align__(16) char aggbuf[128 * 256];    // 32 KB bf16 rows
    __shared__ __align__(16) char hblk[DSPAN * 512];    // 32 KB f32 accum
    __shared__ uint2 binlist[BLMAX];                    // 7168 B
    __shared__ int pcarr[NRMAX];
    __shared__ int segb[NRMAX + 1];

    int b = blockIdx.x;
    int rg = b / NDBLK;
    int dblk = b - rg * NDBLK;
    int dst0 = dblk * DSPAN;
    int r0 = (rg * R_AUG) / RSPLIT;
    int r1 = ((rg + 1) * R_AUG) / RSPLIT;
    int NR = r1 - r0;                                   /* 12 or 13 */

    int t = threadIdx.x, w = t >> 6, lane = t & 63;
    int lr = lane & 15, lq = lane >> 4;
    int no = w * 32;
    int prow = ((lr >> 2) << 3) + (lr & 3);
    int s = (w << 2) | lq;          /* stream 0..15 */
    int sl = lane & 15;             /* lane within stream */

    // ---------- prologue step 1: per-rel degree + padded counts ----------
    int i1 = dst0 + lane;     if (i1 > N_NODES) i1 = N_NODES;
    int i2 = dst0 + lane + 1; if (i2 > N_NODES) i2 = N_NODES;
    int B0[4], DG[4];
    #pragma unroll
    for (int p = 0; p < 4; p++) {
        int ri = w + 4 * p;
        B0[p] = 0; DG[p] = 0;
        if (ri < NR) {
            int r = r0 + ri;
            B0[p] = binoff[r * N_NODES + i1];
            DG[p] = binoff[r * N_NODES + i2] - B0[p];
        }
        unsigned long long mask = __ballot(DG[p] > 0);
        if (ri < NR && lane == 0) pcarr[ri] = (__popcll(mask) + 15) & ~15;
    }
    __syncthreads();

    // ---------- prologue step 2: prefix over rel segments ----------
    if (w == 0) {
        int v = (lane < NR) ? pcarr[lane] : 0;
        int incl = v;
        #pragma unroll
        for (int off = 1; off < 64; off <<= 1) {
            int u = __shfl_up(incl, off, 64);
            if (lane >= off) incl += u;
        }
        if (lane < NR) segb[lane] = incl - v;
        if (lane == NR - 1) segb[NR] = incl;
    }
    __syncthreads();
    int nbtot0 = segb[NR];                              /* multiple of 16 */
    int nbtotP = (nbtot0 + 127) & ~127;                 /* pad to chunk multiple */

    // ---------- prologue step 3: entries + per-rel pads + block pads; zero hblk ----------
    #pragma unroll
    for (int p = 0; p < 4; p++) {
        int ri = w + 4 * p;
        unsigned long long mask = __ballot(DG[p] > 0);
        if (ri < NR) {
            int cnt = __popcll(mask);
            int pos = __popcll(mask & ((1ull << lane) - 1ull));
            int sb = segb[ri];
            if (DG[p] > 0) {
                uint2 e;
                e.x = (unsigned)B0[p];
                e.y = ((unsigned)ri << 26) | ((unsigned)lane << 20) | (unsigned)DG[p];
                binlist[sb + pos] = e;
            }
            int padded = pcarr[ri];
            if (lane >= cnt && lane < padded) {
                uint2 z = {0u, 0u};
                binlist[sb + lane] = z;
            }
        }
    }
    for (int i = nbtot0 + t; i < nbtotP; i += 256) {
        uint2 z = {0u, 0u};
        binlist[i] = z;
    }
    for (int i = t * 16; i < DSPAN * 512; i += 4096) {
        float4 z = {0.f, 0.f, 0.f, 0.f};
        *(float4*)(hblk + i) = z;
    }
    __syncthreads();

    // ---------- W fragment loader (verified prow-permuted layout) ----------
    auto loadW = [&](int r, bf16x8* W0, bf16x8* W1) {
        const unsigned short* Wr = Wt + ((size_t)r << 14);
        #pragma unroll
        for (int ks = 0; ks < 4; ks++) {
            size_t kb = (size_t)(ks << 5) + (lq << 3);
            W0[ks] = *(const bf16x8*)(Wr + (size_t)(no + prow) * D + kb);
            W1[ks] = *(const bf16x8*)(Wr + (size_t)(no + prow + 4) * D + kb);
        }
    };

    // ---------- chunk loop (all trip counts compile-time) ----------
    int nchunks = nbtotP >> 7;
    for (int c = 0; c < nchunks; c++) {
        int cbase = c << 7;

        // ===== stage A: flat-issue aggregation, 2 groups x 4 rows per stream =====
        #pragma unroll
        for (int grp = 0; grp < 2; grp++) {
            uint2 ent[4];
            #pragma unroll
            for (int j = 0; j < 4; j++)
                ent[j] = binlist[cbase + (((grp << 2) + j) << 4) + s];
            unsigned dgv[4]; int e0[4], e1[4], e2[4];
            #pragma unroll
            for (int j = 0; j < 4; j++) {
                dgv[j] = ent[j].y & 0xFFFFFu;
                unsigned bx = ent[j].x;
                e0[j] = esrc[bx];                                  // pads: esrc[0], harmless
                e1[j] = esrc[bx + (dgv[j] > 1u ? 1u : 0u)];        // clamped, branch-free
                e2[j] = esrc[bx + (dgv[j] > 2u ? 2u : 0u)];
            }
            uint4 g0[4], g1[4];
            #pragma unroll
            for (int j = 0; j < 4; j++)
                g0[j] = *(const uint4*)(xb + ((size_t)e0[j] << 7) + (sl << 3));
            #pragma unroll
            for (int j = 0; j < 4; j++)
                g1[j] = *(const uint4*)(xb + ((size_t)e1[j] << 7) + (sl << 3));
            #pragma unroll
            for (int j = 0; j < 4; j++) {
                int row = (((grp << 2) + j) << 4) + s;
                char* dp = aggbuf + ((row * 256 + (sl << 4)) ^ ((row & 7) << 4));
                unsigned dg = dgv[j];
                if (dg == 0u) { uint4 z = {0u,0u,0u,0u}; *(uint4*)dp = z; continue; }
                if (dg == 1u) { *(uint4*)dp = g0[j]; continue; }
                float a0 = bf2f((unsigned short)(g0[j].x & 0xFFFFu)) + bf2f((unsigned short)(g1[j].x & 0xFFFFu));
                float a1 = bf2f((unsigned short)(g0[j].x >> 16))     + bf2f((unsigned short)(g1[j].x >> 16));
                float a2 = bf2f((unsigned short)(g0[j].y & 0xFFFFu)) + bf2f((unsigned short)(g1[j].y & 0xFFFFu));
                float a3 = bf2f((unsigned short)(g0[j].y >> 16))     + bf2f((unsigned short)(g1[j].y >> 16));
                float a4 = bf2f((unsigned short)(g0[j].z & 0xFFFFu)) + bf2f((unsigned short)(g1[j].z & 0xFFFFu));
                float a5 = bf2f((unsigned short)(g0[j].z >> 16))     + bf2f((unsigned short)(g1[j].z >> 16));
                float a6 = bf2f((unsigned short)(g0[j].w & 0xFFFFu)) + bf2f((unsigned short)(g1[j].w & 0xFFFFu));
                float a7 = bf2f((unsigned short)(g0[j].w >> 16))     + bf2f((unsigned short)(g1[j].w >> 16));
                if (dg > 2u) {
                    uint4 g2 = *(const uint4*)(xb + ((size_t)e2[j] << 7) + (sl << 3));
                    a0 += bf2f((unsigned short)(g2.x & 0xFFFFu));
                    a1 += bf2f((unsigned short)(g2.x >> 16));
                    a2 += bf2f((unsigned short)(g2.y & 0xFFFFu));
                    a3 += bf2f((unsigned short)(g2.y >> 16));
                    a4 += bf2f((unsigned short)(g2.z & 0xFFFFu));
                    a5 += bf2f((unsigned short)(g2.z >> 16));
                    a6 += bf2f((unsigned short)(g2.w & 0xFFFFu));
                    a7 += bf2f((unsigned short)(g2.w >> 16));
                    for (unsigned k = 3; k < dg; k++) {            // ~0.3% of bins
                        int sk = esrc[ent[j].x + k];
                        uint4 gk = *(const uint4*)(xb + ((size_t)sk << 7) + (sl << 3));
                        a0 += bf2f((unsigned short)(gk.x & 0xFFFFu));
                        a1 += bf2f((unsigned short)(gk.x >> 16));
                        a2 += bf2f((unsigned short)(gk.y & 0xFFFFu));
                        a3 += bf2f((unsigned short)(gk.y >> 16));
                        a4 += bf2f((unsigned short)(gk.z & 0xFFFFu));
                        a5 += bf2f((unsigned short)(gk.z >> 16));
                        a6 += bf2f((unsigned short)(gk.w & 0xFFFFu));
                        a7 += bf2f((unsigned short)(gk.w >> 16));
                    }
                }
                float scl = 1.0f / (float)dg;
                uint4 o;
                o.x = (unsigned)f2bf(a0 * scl) | ((unsigned)f2bf(a1 * scl) << 16);
                o.y = (unsigned)f2bf(a2 * scl) | ((unsigned)f2bf(a3 * scl) << 16);
                o.z = (unsigned)f2bf(a4 * scl) | ((unsigned)f2bf(a5 * scl) << 16);
                o.w = (unsigned)f2bf(a6 * scl) | ((unsigned)f2bf(a7 * scl) << 16);
                *(uint4*)dp = o;
            }
        }
        __syncthreads();

        // ===== stage B: 8 tiles, W double-buffered (prefetch t+1 during MFMA t) =====
        bf16x8 WA0[4], WA1[4], WB0[4], WB1[4];
        {
            unsigned riA = binlist[cbase].y >> 26;
            loadW(r0 + (int)riA, WA0, WA1);
        }
        #pragma unroll
        for (int tt = 0; tt < 8; tt++) {
            int tb = cbase + (tt << 4);
            if (tt < 7) {
                unsigned riN = binlist[tb + 16].y >> 26;
                loadW(r0 + (int)riN, WB0, WB1);
            }
            uint2 e = binlist[tb + lr];
            int dloc = (e.y >> 20) & 63;
            unsigned dg = e.y & 0xFFFFFu;
            f32x4 c0 = {}, c1 = {};
            int rloc = (tt << 4) + lr;
            #pragma unroll
            for (int ks = 0; ks < 4; ks++) {
                bf16x8 a = *(const bf16x8*)(aggbuf +
                              ((rloc * 256 + (ks << 6) + (lq << 4)) ^ ((rloc & 7) << 4)));
                c0 = __builtin_amdgcn_mfma_f32_16x16x32_bf16(WA0[ks], a, c0, 0, 0, 0);
                c1 = __builtin_amdgcn_mfma_f32_16x16x32_bf16(WA1[ks], a, c1, 0, 0, 0);
            }
            if (dg) {
                int cb = (no + lq * 8) * 4;
                int sw = (dloc & 7) << 4;
                char* hp0 = hblk + ((dloc * 512 + cb) ^ sw);
                char* hp1 = hblk + ((dloc * 512 + cb + 16) ^ sw);
                float4 h0 = *(float4*)hp0;
                h0.x += c0[0]; h0.y += c0[1]; h0.z += c0[2]; h0.w += c0[3];
                *(float4*)hp0 = h0;
                float4 h1 = *(float4*)hp1;
                h1.x += c1[0]; h1.y += c1[1]; h1.z += c1[2]; h1.w += c1[3];
                *(float4*)hp1 = h1;
            }
            #pragma unroll
            for (int ks = 0; ks < 4; ks++) { WA0[ks] = WB0[ks]; WA1[ks] = WB1[ks]; }
        }
        __syncthreads();
    }

    // ---------- writeback hblk -> hpart[rg] ----------
    {
        int row = t >> 2, seg = t & 3;
        int dst = dst0 + row;
        if (dst < N_NODES) {
            float* outp = hpart + ((size_t)rg * N_NODES + dst) * D + seg * 32;
            int sw = (row & 7) << 4;
            #pragma unroll
            for (int q = 0; q < 8; q++) {
                float4 v = *(float4*)(hblk + ((row * 512 + seg * 128 + q * 16) ^ sw));
                *(float4*)(outp + q * 4) = v;
            }
        }
    }
}

// ---------------- finish: h = act(sum_s hpart[s] + bias) ----------------

__global__ __launch_bounds__(256) void finish(const float* __restrict__ hpart,
                                              const float* __restrict__ bias,
                                              float* __restrict__ hf,
                                              unsigned short* __restrict__ hb,
                                              int dorelu) {
    int i0 = (blockIdx.x * 256 + threadIdx.x) * 8;      // grid 625 covers N_NODES*D exactly
    int c0 = i0 & 127;
    float4 b0 = *(const float4*)(bias + c0), b1 = *(const float4*)(bias + c0 + 4);
    float v0 = b0.x, v1 = b0.y, v2 = b0.z, v3 = b0.w;
    float v4 = b1.x, v5 = b1.y, v6 = b1.z, v7 = b1.w;
    #pragma unroll
    for (int s = 0; s < RSPLIT; s++) {
        const float* p = hpart + (size_t)s * N_NODES * D + i0;
        float4 x0 = *(const float4*)p, x1 = *(const float4*)(p + 4);
        v0 += x0.x; v1 += x0.y; v2 += x0.z; v3 += x0.w;
        v4 += x1.x; v5 += x1.y; v6 += x1.z; v7 += x1.w;
    }
    if (dorelu) {
        uint4 p;
        p.x = (unsigned)f2bf(fmaxf(v0, 0.f)) | ((unsigned)f2bf(fmaxf(v1, 0.f)) << 16);
        p.y = (unsigned)f2bf(fmaxf(v2, 0.f)) | ((unsigned)f2bf(fmaxf(v3, 0.f)) << 16);
        p.z = (unsigned)f2bf(fmaxf(v4, 0.f)) | ((unsigned)f2bf(fmaxf(v5, 0.f)) << 16);
        p.w = (unsigned)f2bf(fmaxf(v6, 0.f)) | ((unsigned)f2bf(fmaxf(v7, 0.f)) << 16);
        *(uint4*)(hb + i0) = p;
    } else {
        float4 o0 = {v0, v1, v2, v3};
        float4 o1 = {v4, v5, v6, v7};
        *(float4*)(hf + i0) = o0;
        *(float4*)(hf + i0 + 4) = o1;
    }
}

// ---------------- scoring: 4 items/wave (16 lanes x 2 float4 each) ----------------

__global__ __launch_bounds__(256) void score_kernel(const int* __restrict__ batch,
                                                    const float* __restrict__ h2,
                                                    const float* __restrict__ rels,
                                                    float* __restrict__ out) {
    int t = threadIdx.x;
    int wv = t >> 6, q = (t & 63) >> 4, sl = t & 15;
    int i = blockIdx.x * 16 + wv * 4 + q;     // grid 4096 covers 65536 exactly
    int bs = batch[3*i], bp = batch[3*i+1], bo = batch[3*i+2];
    const float* sp = h2   + (size_t)bs * D + sl * 8;
    const float* pp = rels + (size_t)bp * D + sl * 8;
    const float* op = h2   + (size_t)bo * D + sl * 8;
    float4 s0 = *(const float4*)sp,      s1 = *(const float4*)(sp + 4);
    float4 p0 = *(const float4*)pp,      p1 = *(const float4*)(pp + 4);
    float4 o0 = *(const float4*)op,      o1 = *(const float4*)(op + 4);
    float v = s0.x * p0.x * o0.x + s0.y * p0.y * o0.y + s0.z * p0.z * o0.z + s0.w * p0.w * o0.w
            + s1.x * p1.x * o1.x + s1.y * p1.y * o1.y + s1.z * p1.z * o1.z + s1.w * p1.w * o1.w;
    #pragma unroll
    for (int off = 8; off > 0; off >>= 1) v += __shfl_down(v, off, 16);
    if (sl == 0) out[i] = v;
}

// ---------------- host ----------------

extern "C" void kernel_launch(void* const* d_in, const int* in_sizes, int n_in,
                              void* d_out, int out_size, void* d_ws, size_t ws_size,
                              hipStream_t stream) {
    const int*   graph = (const int*)  d_in[0];
    const int*   batch = (const int*)  d_in[1];
    const float* emb   = (const float*)d_in[2];
    const float* W1    = (const float*)d_in[3];
    const float* b1    = (const float*)d_in[4];
    const float* W2    = (const float*)d_in[5];
    const float* b2    = (const float*)d_in[6];
    const float* rels  = (const float*)d_in[7];
    float* out = (float*)d_out;

    char* base = (char*)d_ws;
    size_t off = 0;
    auto take = [&](size_t bytes) -> char* {
        char* q = base + off;
        off += (bytes + 255) & ~(size_t)255;
        return q;
    };
    int*            deg     = (int*)           take((size_t)NP * 4);
    int*            binoff  = (int*)           take((size_t)(NP + 1) * 4);
    int*            cursor  = (int*)           take((size_t)NP * 4);
    int*            ppart   = (int*)           take((size_t)NPB4 * 4);
    unsigned short* esrc    = (unsigned short*)take((size_t)E_AUG * 2);
    unsigned short* xb      = (unsigned short*)take((size_t)N_NODES * D * 2);
    unsigned short* h1b     = (unsigned short*)take((size_t)N_NODES * D * 2);
    float*          h2      = (float*)         take((size_t)N_NODES * D * 4);
    unsigned short* W1t     = (unsigned short*)take((size_t)R_AUG * D * D * 2);
    unsigned short* W2t     = (unsigned short*)take((size_t)R_AUG * D * D * 2);
    float*          hpart   = (float*)         take((size_t)RSPLIT * N_NODES * D * 4);

    hipMemsetAsync(deg, 0, (size_t)NP * 4, stream);
    prep_all<<<dim3(HIST_BLOCKS + TW_BLOCKS + PREPX_BLOCKS), 256, 0, stream>>>(
        emb, xb, W1, W2, W1t, W2t, graph, deg);
    scan_a<<<dim3(NPB4), 256, 0, stream>>>(deg, binoff, ppart);
    scan_b<<<dim3(1), 256, 0, stream>>>(ppart, binoff);
    scan_c<<<dim3(NPB4), 256, 0, stream>>>(binoff, ppart, cursor);
    scatter_edges<<<dim3(SCAT_BLOCKS), 256, 0, stream>>>(graph, cursor, esrc);

    fused_layer<<<dim3(FUSE_BLOCKS), 256, 0, stream>>>(xb, W1t, binoff, esrc, hpart);
    finish<<<dim3(625), 256, 0, stream>>>(hpart, b1, (float*)0, h1b, 1);
    fused_layer<<<dim3(FUSE_BLOCKS), 256, 0, stream>>>(h1b, W2t, binoff, esrc, hpart);
    finish<<<dim3(625), 256, 0, stream>>>(hpart, b2, h2, (unsigned short*)0, 0);
    score_kernel<<<dim3(N_BATCH / 16), 256, 0, stream>>>(batch, h2, rels, out);
}

// Round 7
// 340.947 us; speedup vs baseline: 1.9220x; 1.8621x over previous
//
#include <hip/hip_runtime.h>

#define N_NODES 10000
#define N_RELS  50
#define R_AUG   101
#define D       128
#define N_EDGES 320000
#define E_AUG   650000   /* 2*N_EDGES + N_NODES */
#define N_BATCH 65536

#define NBINS   N_NODES
#define NSB     ((NBINS + 255) / 256)        /* 40 dst-bin scan blocks */
#define NP      (R_AUG * N_NODES)            /* 1,010,000 (rel,src) pairs */
#define NPB4    ((NP + 1023) / 1024)         /* 987 pair-scan blocks (4 elem/thread) */
#define BSPAN   256                          /* rows per gemm block (512->256: drain-tail 67%->87% util) */
#define GEMM_NBLK (101 + (E_AUG + BSPAN - 1) / BSPAN)  /* 2641 worst-case */
#define SCAT_BLOCKS ((E_AUG + 255) / 256)    /* 2540 */

/* fused prep kernel block ranges: hist FIRST (latency-bound atomics start at t=0,
   bandwidth work overlaps behind) */
#define HIST_BLOCKS  2540                    /* ceil(E_AUG/256) */
#define TW_BLOCKS    808                     /* 2*2*(2*R_AUG) */
#define PREPX_BLOCKS 1250                    /* N_NODES*D/(256*4) */

typedef short bf16x8 __attribute__((ext_vector_type(8)));
typedef float f32x4  __attribute__((ext_vector_type(4)));

__device__ __forceinline__ unsigned short f2bf(float f) {
    union { float f; unsigned int u; } v; v.f = f;
    unsigned int r = (v.u + 0x7FFFu + ((v.u >> 16) & 1u)) >> 16;
    return (unsigned short)r;
}
__device__ __forceinline__ float bf2f(unsigned short h) {
    union { unsigned int u; float f; } v; v.u = ((unsigned int)h) << 16;
    return v.f;
}
__device__ __forceinline__ float u2f(unsigned int u) {
    union { unsigned int u; float f; } v; v.u = u; return v.f;
}
__device__ __forceinline__ unsigned int f2u(float f) {
    union { float f; unsigned int u; } v; v.f = f; return v.u;
}

__device__ __forceinline__ void decode_edge(const int* __restrict__ g, int e,
                                            int& src, int& rel, int& dst) {
    if (e < N_EDGES)            { src = g[3*e];     rel = g[3*e+1];          dst = g[3*e+2]; }
    else if (e < 2*N_EDGES)     { int b = e - N_EDGES;
                                  src = g[3*b+2];   rel = g[3*b+1] + N_RELS; dst = g[3*b];   }
    else                        { int n = e - 2*N_EDGES; src = n; dst = n; rel = 2*N_RELS;   }
}

// paired relation: edge with rel=r,src=x exists  <=>  deg[pair(r)][x] > 0
__device__ __forceinline__ int pair_rel(int r) {
    return (r < N_RELS) ? r + N_RELS : (r < 2 * N_RELS ? r - N_RELS : r);
}

// ---------------- fused prep: deg_hist | transpose_w | x->bf16 ----------------

__global__ __launch_bounds__(256) void prep_all(const float* __restrict__ x,
                                                unsigned short* __restrict__ xb,
                                                const float* __restrict__ W1,
                                                const float* __restrict__ W2,
                                                unsigned short* __restrict__ W1t,
                                                unsigned short* __restrict__ W2t,
                                                const int* __restrict__ g,
                                                int* __restrict__ deg) {
    __shared__ float tile[64][65];
    int b = blockIdx.x, t = threadIdx.x;
    if (b < HIST_BLOCKS) {
        int e = b * 256 + t;
        if (e < E_AUG) {
            int src, rel, dst;
            decode_edge(g, e, src, rel, dst);
            atomicAdd(&deg[rel * N_NODES + dst], 1);
        }
    } else if (b < HIST_BLOCKS + TW_BLOCKS) {
        int q = b - HIST_BLOCKS;
        int d0 = (q & 1) * 64, o0 = ((q >> 1) & 1) * 64;
        int z = q >> 2;                                  /* 0..201 */
        const float* W = (z < R_AUG) ? W1 : W2;
        unsigned short* Wt = (z < R_AUG) ? W1t : W2t;
        int r = (z < R_AUG) ? z : (z - R_AUG);
        int tx = t & 63, ty = t >> 6;
        #pragma unroll
        for (int i = ty; i < 64; i += 4)
            tile[i][tx] = W[((size_t)r * D + (d0 + i)) * D + (o0 + tx)];
        __syncthreads();
        #pragma unroll
        for (int i = ty; i < 64; i += 4)
            Wt[((size_t)r * D + (o0 + i)) * D + (d0 + tx)] = f2bf(tile[tx][i]);
    } else {
        int i = (b - HIST_BLOCKS - TW_BLOCKS) * 1024 + t * 4;  // covers N_NODES*D exactly
        float4 xv = *(const float4*)(x + i);
        ushort4 o;
        o.x = f2bf(xv.x); o.y = f2bf(xv.y); o.z = f2bf(xv.z); o.w = f2bf(xv.w);
        *(ushort4*)(xb + i) = o;
    }
}

// ---- scan stage A: dst-bin block scan | pair block scan (flag = deg[pair]>0, 4/thread) ----

__global__ __launch_bounds__(256) void scan_a(const int* __restrict__ deg,
                                              int* __restrict__ offs,
                                              int* __restrict__ part,
                                              int* __restrict__ S,
                                              int* __restrict__ ppart) {
    __shared__ int wsum[4];
    int t = threadIdx.x, lane = t & 63, w = t >> 6;
    int b = blockIdx.x;
    if (b < NSB) {
        int i = b * 256 + t;
        int v = 0;
        if (i < NBINS) {
            for (int r = 0; r < R_AUG; r++) v += deg[r * N_NODES + i];
        }
        int incl = v;
        #pragma unroll
        for (int off = 1; off < 64; off <<= 1) {
            int u = __shfl_up(incl, off, 64);
            if (lane >= off) incl += u;
        }
        if (lane == 63) wsum[w] = incl;
        __syncthreads();
        int woff = 0;
        for (int k = 0; k < w; k++) woff += wsum[k];
        if (i < NBINS) offs[i] = woff + incl - v;
        if (t == 255) part[b] = woff + incl;
    } else {
        int pb = b - NSB;
        int i0 = pb * 1024 + t * 4;
        int4 f = {0, 0, 0, 0};
        if (i0 < NP) {
            int r = i0 / N_NODES;
            int xx = i0 - r * N_NODES;                  // 4-pack never crosses r (10000%4==0)
            const int* dp = deg + pair_rel(r) * N_NODES + xx;
            if (i0 + 3 < NP) {
                int4 d = *(const int4*)dp;
                f.x = d.x > 0; f.y = d.y > 0; f.z = d.z > 0; f.w = d.w > 0;
            } else {
                f.x = dp[0] > 0;
                if (i0 + 1 < NP) f.y = dp[1] > 0;
                if (i0 + 2 < NP) f.z = dp[2] > 0;
            }
        }
        int e1 = f.x, e2 = f.x + f.y, e3 = e2 + f.z, v = e3 + f.w;
        int incl = v;
        #pragma unroll
        for (int off = 1; off < 64; off <<= 1) {
            int u = __shfl_up(incl, off, 64);
            if (lane >= off) incl += u;
        }
        if (lane == 63) wsum[w] = incl;
        __syncthreads();
        int woff = 0;
        for (int k = 0; k < w; k++) woff += wsum[k];
        int texcl = woff + incl - v;
        if (i0 + 3 < NP) {
            int4 o = {texcl, texcl + e1, texcl + e2, texcl + e3};
            *(int4*)(S + i0) = o;
        } else if (i0 < NP) {
            S[i0] = texcl;
            if (i0 + 1 < NP) S[i0 + 1] = texcl + e1;
            if (i0 + 2 < NP) S[i0 + 2] = texcl + e2;
        }
        if (t == 255) ppart[pb] = woff + incl;
    }
}

// ---- scan stage B: block 0 scans part[NSB]; block 1 serial-carry scans ppart[NPB4] ----

__global__ __launch_bounds__(256) void scan_b(int* __restrict__ part,
                                              int* __restrict__ ppart,
                                              int* __restrict__ S) {
    __shared__ int wsum[4];
    int t = threadIdx.x, lane = t & 63, w = t >> 6;
    if (blockIdx.x == 0) {
        int v = (t < NSB) ? part[t] : 0;
        int incl = v;
        #pragma unroll
        for (int off = 1; off < 64; off <<= 1) {
            int u = __shfl_up(incl, off, 64);
            if (lane >= off) incl += u;
        }
        if (lane == 63) wsum[w] = incl;
        __syncthreads();
        int woff = 0;
        for (int k = 0; k < w; k++) woff += wsum[k];
        if (t < NSB) part[t] = woff + incl - v;
    } else {
        int carry = 0;
        for (int base = 0; base < NPB4; base += 256) {
            int i = base + t;
            int v = (i < NPB4) ? ppart[i] : 0;
            int incl = v;
            #pragma unroll
            for (int off = 1; off < 64; off <<= 1) {
                int u = __shfl_up(incl, off, 64);
                if (lane >= off) incl += u;
            }
            if (lane == 63) wsum[w] = incl;
            __syncthreads();
            int woff = 0;
            for (int k = 0; k < w; k++) woff += wsum[k];
            if (i < NPB4) ppart[i] = carry + woff + incl - v;
            carry += wsum[0] + wsum[1] + wsum[2] + wsum[3];
            __syncthreads();
        }
        if (t == 0) S[NP] = carry;
    }
}

// ---- scan stage C: dst-bin add+cursor | pair add+compact (4 elem/thread) ----

__global__ __launch_bounds__(256) void scan_c(int* __restrict__ offs,
                                              const int* __restrict__ part,
                                              int* __restrict__ cursor,
                                              const int* __restrict__ deg,
                                              int* __restrict__ S,
                                              const int* __restrict__ ppart,
                                              int* __restrict__ pair_src) {
    int b = blockIdx.x, t = threadIdx.x;
    if (b < NSB) {
        int i = b * 256 + t;
        if (i < NBINS) {
            int v = offs[i] + part[i >> 8];
            offs[i] = v;
            cursor[i] = v;
        }
        if (i == 0) offs[NBINS] = E_AUG;
    } else {
        int pb = b - NSB;
        int i0 = pb * 1024 + t * 4;
        if (i0 >= NP) return;
        int pp = ppart[pb];
        int r = i0 / N_NODES;
        int xx = i0 - r * N_NODES;
        const int* dp = deg + pair_rel(r) * N_NODES + xx;
        if (i0 + 3 < NP) {
            int4 sv = *(int4*)(S + i0);
            sv.x += pp; sv.y += pp; sv.z += pp; sv.w += pp;
            *(int4*)(S + i0) = sv;
            int4 d = *(const int4*)dp;
            if (d.x > 0) pair_src[sv.x] = xx;
            if (d.y > 0) pair_src[sv.y] = xx + 1;
            if (d.z > 0) pair_src[sv.z] = xx + 2;
            if (d.w > 0) pair_src[sv.w] = xx + 3;
        } else {
            for (int k = 0; k < 4; k++) {
                int i = i0 + k;
                if (i >= NP) break;
                int s = S[i] + pp;
                S[i] = s;
                if (dp[k] > 0) pair_src[s] = xx + k;
            }
        }
    }
}

// ---------------- fused [block-table | edge scatter] ----------------

__global__ __launch_bounds__(256) void scatter_blk(const int* __restrict__ g,
                                                   const int* __restrict__ deg,
                                                   const int* __restrict__ S,
                                                   int* __restrict__ cursor,
                                                   uint2* __restrict__ sorted,
                                                   int* __restrict__ rowbase,
                                                   int* __restrict__ rowcnt,
                                                   int* __restrict__ blkoffs) {
    int b = blockIdx.x, t = threadIdx.x;
    if (b == 0) {
        __shared__ int wsum[4];
        int lane = t & 63, w = t >> 6;
        int nb = 0;
        if (t < R_AUG) {
            int base = S[t * N_NODES];
            int nxt  = S[(t + 1) * N_NODES];     /* t==100 -> S[NP] = total */
            rowbase[t] = base;
            rowcnt[t]  = nxt - base;
            nb = (nxt - base + BSPAN - 1) / BSPAN;
        }
        int incl = nb;
        #pragma unroll
        for (int off = 1; off < 64; off <<= 1) {
            int u = __shfl_up(incl, off, 64);
            if (lane >= off) incl += u;
        }
        if (lane == 63) wsum[w] = incl;
        __syncthreads();
        int woff = 0;
        for (int k = 0; k < w; k++) woff += wsum[k];
        if (t < R_AUG) blkoffs[t] = woff + incl - nb;
        if (t == R_AUG) blkoffs[R_AUG] = woff + incl;   /* total blocks */
        return;
    }
    int e = (b - 1) * 256 + t;
    if (e >= E_AUG) return;
    int src, rel, dst;
    decode_edge(g, e, src, rel, dst);
    int pos = atomicAdd(&cursor[dst], 1);
    int dg = deg[rel * N_NODES + dst];          // >= 1 by construction
    uint2 rec;
    rec.x = (unsigned)S[rel * N_NODES + src];   // compact Z row
    rec.y = f2u(1.0f / (float)dg);
    sorted[pos] = rec;
}

// ---------------- compact GEMM: Zc[row][o] = xb[pair_src[row]][:] @ W[rel(row)][:][o] ----------------
// Fixed grid; block -> (rel, 256-row span) via binary search in blkoffs.
// Wave w: cols (w&1)*64..+64, tile parity w>>1 (8 tiles of 16 rows each).
// 8 tile indices preloaded; next-tile A prefetch; 4 A-loads : 16 MFMA.
// W rows permuted at load so lane (lr,lq) holds cols no+lq*8+{0..7} of its row.
// BSPAN=256 (was 512): ~2100 blocks over 1024 concurrent slots -> 2.05/slot
// vs 1.34/slot -> drain-tail utilization 67% -> ~87%.

__global__ __launch_bounds__(256, 4) void gemm_compact(const unsigned short* __restrict__ xb,
                                                       const unsigned short* __restrict__ Wt,
                                                       const int* __restrict__ pair_src,
                                                       const int* __restrict__ rowbase,
                                                       const int* __restrict__ rowcnt,
                                                       const int* __restrict__ blkoffs,
                                                       unsigned short* __restrict__ Zc) {
    int b = blockIdx.x;
    if (b >= blkoffs[R_AUG]) return;
    int lo = 0, hi = R_AUG;
    while (hi - lo > 1) {
        int mid = (lo + hi) >> 1;
        if (blkoffs[mid] <= b) lo = mid; else hi = mid;
    }
    int r = lo;
    int lb = b - blkoffs[r];
    int rbase = rowbase[r] + lb * BSPAN;
    int nrows = rowcnt[r] - lb * BSPAN; if (nrows > BSPAN) nrows = BSPAN;

    int t = threadIdx.x, wave = t >> 6, lane = t & 63;
    int lr = lane & 15, lq = lane >> 4;
    int no = (wave & 1) * 64;
    int tp = wave >> 1;
    const unsigned short* Wr = Wt + (size_t)r * D * D;

    // preload all 8 tile indices (independent loads)
    int srcs[8];
    #pragma unroll
    for (int i = 0; i < 8; i++) {
        int row = (tp + 2 * i) * 16 + lr;
        srcs[i] = pair_src[rbase + (row < nrows ? row : 0)];
    }

    int prow = ((lr >> 2) << 3) + (lr & 3);
    bf16x8 w0[4], w1[4], w2[4], w3[4];
    #pragma unroll
    for (int ks = 0; ks < 4; ks++) {
        size_t kb = ks * 32 + lq * 8;
        w0[ks] = *(const bf16x8*)(Wr + (size_t)(no + prow) * D + kb);
        w1[ks] = *(const bf16x8*)(Wr + (size_t)(no + prow + 4) * D + kb);
        w2[ks] = *(const bf16x8*)(Wr + (size_t)(no + 32 + prow) * D + kb);
        w3[ks] = *(const bf16x8*)(Wr + (size_t)(no + 32 + prow + 4) * D + kb);
    }

    bf16x8 a[4];
    {
        const unsigned short* x0 = xb + (size_t)srcs[0] * D + lq * 8;
        #pragma unroll
        for (int ks = 0; ks < 4; ks++) a[ks] = *(const bf16x8*)(x0 + ks * 32);
    }

    #pragma unroll
    for (int i = 0; i < 8; i++) {
        int tile = tp + 2 * i;
        if (tile * 16 >= nrows) break;                  // wave-uniform

        bf16x8 an[4];                                   // prefetch next tile's A
        {
            int ni = (i < 7) ? i + 1 : 7;
            const unsigned short* xn = xb + (size_t)srcs[ni] * D + lq * 8;
            #pragma unroll
            for (int ks = 0; ks < 4; ks++) an[ks] = *(const bf16x8*)(xn + ks * 32);
        }

        f32x4 c0 = {}, c1 = {}, c2 = {}, c3 = {};
        #pragma unroll
        for (int ks = 0; ks < 4; ks++) {
            c0 = __builtin_amdgcn_mfma_f32_16x16x32_bf16(w0[ks], a[ks], c0, 0, 0, 0);
            c1 = __builtin_amdgcn_mfma_f32_16x16x32_bf16(w1[ks], a[ks], c1, 0, 0, 0);
            c2 = __builtin_amdgcn_mfma_f32_16x16x32_bf16(w2[ks], a[ks], c2, 0, 0, 0);
            c3 = __builtin_amdgcn_mfma_f32_16x16x32_bf16(w3[ks], a[ks], c3, 0, 0, 0);
        }
        int row = tile * 16 + lr;
        if (row < nrows) {
            unsigned short* zrow = Zc + ((size_t)(rbase + row) << 7);
            uint4 p0, p1;
            p0.x = (unsigned)f2bf(c0[0]) | ((unsigned)f2bf(c0[1]) << 16);
            p0.y = (unsigned)f2bf(c0[2]) | ((unsigned)f2bf(c0[3]) << 16);
            p0.z = (unsigned)f2bf(c1[0]) | ((unsigned)f2bf(c1[1]) << 16);
            p0.w = (unsigned)f2bf(c1[2]) | ((unsigned)f2bf(c1[3]) << 16);
            p1.x = (unsigned)f2bf(c2[0]) | ((unsigned)f2bf(c2[1]) << 16);
            p1.y = (unsigned)f2bf(c2[2]) | ((unsigned)f2bf(c2[3]) << 16);
            p1.z = (unsigned)f2bf(c3[0]) | ((unsigned)f2bf(c3[1]) << 16);
            p1.w = (unsigned)f2bf(c3[2]) | ((unsigned)f2bf(c3[3]) << 16);
            *(uint4*)(zrow + no + lq * 8) = p0;
            *(uint4*)(zrow + no + 32 + lq * 8) = p1;
        }
        #pragma unroll
        for (int ks = 0; ks < 4; ks++) a[ks] = an[ks];
    }
}

// ---------------- aggregation: one wave per dst, 8 edges in flight ----------------

__global__ __launch_bounds__(256) void agg_pass(const uint2* __restrict__ sorted,
                                                const int* __restrict__ offs,
                                                const unsigned short* __restrict__ Zc,
                                                const float* __restrict__ bias,
                                                float* __restrict__ hf,
                                                unsigned short* __restrict__ hb,
                                                int dorelu) {
    int w = threadIdx.x >> 6, lane = threadIdx.x & 63;
    int dst = blockIdx.x * 4 + w;
    if (dst >= N_NODES) return;
    int e0 = offs[dst], e1 = offs[dst + 1];
    int g = lane >> 3, s = lane & 7;
    float acc[16] = {};

    for (int base = e0; base < e1; base += 64) {
        int n = e1 - base; if (n > 64) n = 64;
        uint2 rec = {0u, 0u};
        if (lane < n) rec = sorted[base + lane];
        int iters = (n + 7) >> 3;
        #pragma unroll 2
        for (int j = 0; j < iters; j++) {
            int ej = j * 8 + g;
            int ec = (ej < n) ? ej : (n - 1);
            unsigned zi = (unsigned)__shfl((int)rec.x, ec, 64);
            unsigned nb = (unsigned)__shfl((int)rec.y, ec, 64);
            float nrm = (ej < n) ? u2f(nb) : 0.0f;
            const unsigned short* zp = Zc + ((size_t)zi << 7) + s * 16;
            uint4 z0 = *(const uint4*)zp;
            uint4 z1 = *(const uint4*)(zp + 8);
            acc[0]  += nrm * bf2f((unsigned short)(z0.x & 0xFFFFu));
            acc[1]  += nrm * bf2f((unsigned short)(z0.x >> 16));
            acc[2]  += nrm * bf2f((unsigned short)(z0.y & 0xFFFFu));
            acc[3]  += nrm * bf2f((unsigned short)(z0.y >> 16));
            acc[4]  += nrm * bf2f((unsigned short)(z0.z & 0xFFFFu));
            acc[5]  += nrm * bf2f((unsigned short)(z0.z >> 16));
            acc[6]  += nrm * bf2f((unsigned short)(z0.w & 0xFFFFu));
            acc[7]  += nrm * bf2f((unsigned short)(z0.w >> 16));
            acc[8]  += nrm * bf2f((unsigned short)(z1.x & 0xFFFFu));
            acc[9]  += nrm * bf2f((unsigned short)(z1.x >> 16));
            acc[10] += nrm * bf2f((unsigned short)(z1.y & 0xFFFFu));
            acc[11] += nrm * bf2f((unsigned short)(z1.y >> 16));
            acc[12] += nrm * bf2f((unsigned short)(z1.z & 0xFFFFu));
            acc[13] += nrm * bf2f((unsigned short)(z1.z >> 16));
            acc[14] += nrm * bf2f((unsigned short)(z1.w & 0xFFFFu));
            acc[15] += nrm * bf2f((unsigned short)(z1.w >> 16));
        }
    }
    #pragma unroll
    for (int k = 0; k < 16; k++) {
        acc[k] += __shfl_down(acc[k], 8, 64);
        acc[k] += __shfl_down(acc[k], 16, 64);
        acc[k] += __shfl_down(acc[k], 32, 64);
    }
    if (g == 0) {
        const float* bp = bias + s * 16;
        float vv[16];
        #pragma unroll
        for (int k = 0; k < 16; k++) vv[k] = bp[k] + acc[k];
        if (dorelu) {
            unsigned short* hp = hb + ((size_t)dst << 7) + s * 16;
            uint4 p0, p1;
            p0.x = (unsigned)f2bf(fmaxf(vv[0], 0.0f))  | ((unsigned)f2bf(fmaxf(vv[1], 0.0f))  << 16);
            p0.y = (unsigned)f2bf(fmaxf(vv[2], 0.0f))  | ((unsigned)f2bf(fmaxf(vv[3], 0.0f))  << 16);
            p0.z = (unsigned)f2bf(fmaxf(vv[4], 0.0f))  | ((unsigned)f2bf(fmaxf(vv[5], 0.0f))  << 16);
            p0.w = (unsigned)f2bf(fmaxf(vv[6], 0.0f))  | ((unsigned)f2bf(fmaxf(vv[7], 0.0f))  << 16);
            p1.x = (unsigned)f2bf(fmaxf(vv[8], 0.0f))  | ((unsigned)f2bf(fmaxf(vv[9], 0.0f))  << 16);
            p1.y = (unsigned)f2bf(fmaxf(vv[10], 0.0f)) | ((unsigned)f2bf(fmaxf(vv[11], 0.0f)) << 16);
            p1.z = (unsigned)f2bf(fmaxf(vv[12], 0.0f)) | ((unsigned)f2bf(fmaxf(vv[13], 0.0f)) << 16);
            p1.w = (unsigned)f2bf(fmaxf(vv[14], 0.0f)) | ((unsigned)f2bf(fmaxf(vv[15], 0.0f)) << 16);
            *(uint4*)hp = p0;
            *(uint4*)(hp + 8) = p1;
        } else {
            float* hp = hf + ((size_t)dst << 7) + s * 16;
            #pragma unroll
            for (int q = 0; q < 4; q++) {
                float4 o = {vv[q * 4], vv[q * 4 + 1], vv[q * 4 + 2], vv[q * 4 + 3]};
                *(float4*)(hp + q * 4) = o;
            }
        }
    }
}

// ---------------- scoring: 4 items/wave (16 lanes x 2 float4 each) ----------------

__global__ __launch_bounds__(256) void score_kernel(const int* __restrict__ batch,
                                                    const float* __restrict__ h2,
                                                    const float* __restrict__ rels,
                                                    float* __restrict__ out) {
    int t = threadIdx.x;
    int wv = t >> 6, q = (t & 63) >> 4, sl = t & 15;
    int i = blockIdx.x * 16 + wv * 4 + q;     // grid 4096 covers 65536 exactly
    int bs = batch[3*i], bp = batch[3*i+1], bo = batch[3*i+2];
    const float* sp = h2   + (size_t)bs * D + sl * 8;
    const float* pp = rels + (size_t)bp * D + sl * 8;
    const float* op = h2   + (size_t)bo * D + sl * 8;
    float4 s0 = *(const float4*)sp,      s1 = *(const float4*)(sp + 4);
    float4 p0 = *(const float4*)pp,      p1 = *(const float4*)(pp + 4);
    float4 o0 = *(const float4*)op,      o1 = *(const float4*)(op + 4);
    float v = s0.x * p0.x * o0.x + s0.y * p0.y * o0.y + s0.z * p0.z * o0.z + s0.w * p0.w * o0.w
            + s1.x * p1.x * o1.x + s1.y * p1.y * o1.y + s1.z * p1.z * o1.z + s1.w * p1.w * o1.w;
    #pragma unroll
    for (int off = 8; off > 0; off >>= 1) v += __shfl_down(v, off, 16);
    if (sl == 0) out[i] = v;
}

// ---------------- host ----------------

extern "C" void kernel_launch(void* const* d_in, const int* in_sizes, int n_in,
                              void* d_out, int out_size, void* d_ws, size_t ws_size,
                              hipStream_t stream) {
    const int*   graph = (const int*)  d_in[0];
    const int*   batch = (const int*)  d_in[1];
    const float* emb   = (const float*)d_in[2];
    const float* W1    = (const float*)d_in[3];
    const float* b1    = (const float*)d_in[4];
    const float* W2    = (const float*)d_in[5];
    const float* b2    = (const float*)d_in[6];
    const float* rels  = (const float*)d_in[7];
    float* out = (float*)d_out;

    char* base = (char*)d_ws;
    size_t off = 0;
    auto take = [&](size_t bytes) -> char* {
        char* q = base + off;
        off += (bytes + 255) & ~(size_t)255;
        return q;
    };
    int*            deg     = (int*)           take((size_t)NP * 4);
    int*            S       = (int*)           take((size_t)(NP + 1) * 4);
    int*            pair_src= (int*)           take((size_t)E_AUG * 4);
    int*            ppart   = (int*)           take((size_t)NPB4 * 4);
    int*            rowbase = (int*)           take((size_t)(R_AUG + 1) * 4);
    int*            rowcnt  = (int*)           take((size_t)(R_AUG + 1) * 4);
    int*            blkoffs = (int*)           take((size_t)(R_AUG + 2) * 4);
    unsigned short* xb      = (unsigned short*)take((size_t)N_NODES * D * 2);
    float*          h2      = (float*)         take((size_t)N_NODES * D * 4);
    unsigned short* h1b     = (unsigned short*)take((size_t)N_NODES * D * 2);
    unsigned short* W1t     = (unsigned short*)take((size_t)R_AUG * D * D * 2);
    unsigned short* W2t     = (unsigned short*)take((size_t)R_AUG * D * D * 2);
    int*            offs    = (int*)           take((size_t)(NBINS + 1) * 4);
    int*            cursor  = (int*)           take((size_t)NBINS * 4);
    int*            part    = (int*)           take((size_t)NSB * 4);
    uint2*          sorted  = (uint2*)         take((size_t)E_AUG * 8);
    unsigned short* Zc      = (unsigned short*)take((size_t)E_AUG * D * 2);  // worst-case 166 MB

    hipMemsetAsync(deg, 0, (size_t)NP * 4, stream);
    prep_all<<<dim3(HIST_BLOCKS + TW_BLOCKS + PREPX_BLOCKS), 256, 0, stream>>>(
        emb, xb, W1, W2, W1t, W2t, graph, deg);
    scan_a<<<dim3(NSB + NPB4), 256, 0, stream>>>(deg, offs, part, S, ppart);
    scan_b<<<dim3(2), 256, 0, stream>>>(part, ppart, S);
    scan_c<<<dim3(NSB + NPB4), 256, 0, stream>>>(offs, part, cursor, deg, S, ppart, pair_src);
    scatter_blk<<<dim3(1 + SCAT_BLOCKS), 256, 0, stream>>>(
        graph, deg, S, cursor, sorted, rowbase, rowcnt, blkoffs);

    gemm_compact<<<dim3(GEMM_NBLK), 256, 0, stream>>>(xb, W1t, pair_src, rowbase, rowcnt, blkoffs, Zc);
    agg_pass<<<dim3((N_NODES + 3) / 4), 256, 0, stream>>>(sorted, offs, Zc, b1, (float*)0, h1b, 1);
    gemm_compact<<<dim3(GEMM_NBLK), 256, 0, stream>>>(h1b, W2t, pair_src, rowbase, rowcnt, blkoffs, Zc);
    agg_pass<<<dim3((N_NODES + 3) / 4), 256, 0, stream>>>(sorted, offs, Zc, b2, h2, (unsigned short*)0, 0);
    score_kernel<<<dim3(N_BATCH / 16), 256, 0, stream>>>(batch, h2, rels, out);
}

// Round 8
// 336.044 us; speedup vs baseline: 1.9500x; 1.0146x over previous
//
#include <hip/hip_runtime.h>

#define N_NODES 10000
#define N_RELS  50
#define R_AUG   101
#define D       128
#define N_EDGES 320000
#define E_AUG   650000   /* 2*N_EDGES + N_NODES */
#define N_BATCH 65536

#define NBINS   N_NODES
#define NSB     ((NBINS + 255) / 256)        /* 40 dst-bin scan blocks */
#define NP      (R_AUG * N_NODES)            /* 1,010,000 (rel,src) pairs */
#define NPB4    ((NP + 1023) / 1024)         /* 987 pair-scan blocks (4 elem/thread) */
#define BSPAN   512                          /* rows per gemm block (measured best; 256 regressed) */
#define GEMM_NBLK (101 + (E_AUG + BSPAN - 1) / BSPAN)  /* 1371 worst-case */
#define SCAT_BLOCKS ((E_AUG + 255) / 256)    /* 2540 */

/* fused prep kernel block ranges: hist FIRST (latency-bound atomics start at t=0,
   bandwidth work overlaps behind) */
#define HIST_BLOCKS  2540                    /* ceil(E_AUG/256) */
#define TW_BLOCKS    808                     /* 2*2*(2*R_AUG) */
#define PREPX_BLOCKS 1250                    /* N_NODES*D/(256*4) */

typedef short bf16x8 __attribute__((ext_vector_type(8)));
typedef float f32x4  __attribute__((ext_vector_type(4)));

__device__ __forceinline__ unsigned short f2bf(float f) {
    union { float f; unsigned int u; } v; v.f = f;
    unsigned int r = (v.u + 0x7FFFu + ((v.u >> 16) & 1u)) >> 16;
    return (unsigned short)r;
}
__device__ __forceinline__ float bf2f(unsigned short h) {
    union { unsigned int u; float f; } v; v.u = ((unsigned int)h) << 16;
    return v.f;
}
__device__ __forceinline__ float u2f(unsigned int u) {
    union { unsigned int u; float f; } v; v.u = u; return v.f;
}
__device__ __forceinline__ unsigned int f2u(float f) {
    union { float f; unsigned int u; } v; v.f = f; return v.u;
}

__device__ __forceinline__ void decode_edge(const int* __restrict__ g, int e,
                                            int& src, int& rel, int& dst) {
    if (e < N_EDGES)            { src = g[3*e];     rel = g[3*e+1];          dst = g[3*e+2]; }
    else if (e < 2*N_EDGES)     { int b = e - N_EDGES;
                                  src = g[3*b+2];   rel = g[3*b+1] + N_RELS; dst = g[3*b];   }
    else                        { int n = e - 2*N_EDGES; src = n; dst = n; rel = 2*N_RELS;   }
}

// paired relation: edge with rel=r,src=x exists  <=>  deg[pair(r)][x] > 0
__device__ __forceinline__ int pair_rel(int r) {
    return (r < N_RELS) ? r + N_RELS : (r < 2 * N_RELS ? r - N_RELS : r);
}

// ---------------- fused prep: deg_hist | transpose_w | x->bf16 ----------------

__global__ __launch_bounds__(256) void prep_all(const float* __restrict__ x,
                                                unsigned short* __restrict__ xb,
                                                const float* __restrict__ W1,
                                                const float* __restrict__ W2,
                                                unsigned short* __restrict__ W1t,
                                                unsigned short* __restrict__ W2t,
                                                const int* __restrict__ g,
                                                int* __restrict__ deg) {
    __shared__ float tile[64][65];
    int b = blockIdx.x, t = threadIdx.x;
    if (b < HIST_BLOCKS) {
        int e = b * 256 + t;
        if (e < E_AUG) {
            int src, rel, dst;
            decode_edge(g, e, src, rel, dst);
            atomicAdd(&deg[rel * N_NODES + dst], 1);
        }
    } else if (b < HIST_BLOCKS + TW_BLOCKS) {
        int q = b - HIST_BLOCKS;
        int d0 = (q & 1) * 64, o0 = ((q >> 1) & 1) * 64;
        int z = q >> 2;                                  /* 0..201 */
        const float* W = (z < R_AUG) ? W1 : W2;
        unsigned short* Wt = (z < R_AUG) ? W1t : W2t;
        int r = (z < R_AUG) ? z : (z - R_AUG);
        int tx = t & 63, ty = t >> 6;
        #pragma unroll
        for (int i = ty; i < 64; i += 4)
            tile[i][tx] = W[((size_t)r * D + (d0 + i)) * D + (o0 + tx)];
        __syncthreads();
        #pragma unroll
        for (int i = ty; i < 64; i += 4)
            Wt[((size_t)r * D + (o0 + i)) * D + (d0 + tx)] = f2bf(tile[tx][i]);
    } else {
        int i = (b - HIST_BLOCKS - TW_BLOCKS) * 1024 + t * 4;  // covers N_NODES*D exactly
        float4 xv = *(const float4*)(x + i);
        ushort4 o;
        o.x = f2bf(xv.x); o.y = f2bf(xv.y); o.z = f2bf(xv.z); o.w = f2bf(xv.w);
        *(ushort4*)(xb + i) = o;
    }
}

// ---- scan stage A: dst-bin block scan | pair block scan (flag = deg[pair]>0, 4/thread) ----

__global__ __launch_bounds__(256) void scan_a(const int* __restrict__ deg,
                                              int* __restrict__ offs,
                                              int* __restrict__ part,
                                              int* __restrict__ S,
                                              int* __restrict__ ppart) {
    __shared__ int wsum[4];
    int t = threadIdx.x, lane = t & 63, w = t >> 6;
    int b = blockIdx.x;
    if (b < NSB) {
        int i = b * 256 + t;
        int v = 0;
        if (i < NBINS) {
            for (int r = 0; r < R_AUG; r++) v += deg[r * N_NODES + i];
        }
        int incl = v;
        #pragma unroll
        for (int off = 1; off < 64; off <<= 1) {
            int u = __shfl_up(incl, off, 64);
            if (lane >= off) incl += u;
        }
        if (lane == 63) wsum[w] = incl;
        __syncthreads();
        int woff = 0;
        for (int k = 0; k < w; k++) woff += wsum[k];
        if (i < NBINS) offs[i] = woff + incl - v;
        if (t == 255) part[b] = woff + incl;
    } else {
        int pb = b - NSB;
        int i0 = pb * 1024 + t * 4;
        int4 f = {0, 0, 0, 0};
        if (i0 < NP) {
            int r = i0 / N_NODES;
            int xx = i0 - r * N_NODES;                  // 4-pack never crosses r (10000%4==0)
            const int* dp = deg + pair_rel(r) * N_NODES + xx;
            if (i0 + 3 < NP) {
                int4 d = *(const int4*)dp;
                f.x = d.x > 0; f.y = d.y > 0; f.z = d.z > 0; f.w = d.w > 0;
            } else {
                f.x = dp[0] > 0;
                if (i0 + 1 < NP) f.y = dp[1] > 0;
                if (i0 + 2 < NP) f.z = dp[2] > 0;
            }
        }
        int e1 = f.x, e2 = f.x + f.y, e3 = e2 + f.z, v = e3 + f.w;
        int incl = v;
        #pragma unroll
        for (int off = 1; off < 64; off <<= 1) {
            int u = __shfl_up(incl, off, 64);
            if (lane >= off) incl += u;
        }
        if (lane == 63) wsum[w] = incl;
        __syncthreads();
        int woff = 0;
        for (int k = 0; k < w; k++) woff += wsum[k];
        int texcl = woff + incl - v;
        if (i0 + 3 < NP) {
            int4 o = {texcl, texcl + e1, texcl + e2, texcl + e3};
            *(int4*)(S + i0) = o;
        } else if (i0 < NP) {
            S[i0] = texcl;
            if (i0 + 1 < NP) S[i0 + 1] = texcl + e1;
            if (i0 + 2 < NP) S[i0 + 2] = texcl + e2;
        }
        if (t == 255) ppart[pb] = woff + incl;
    }
}

// ---- scan stage B: block 0 scans part[NSB]; block 1 serial-carry scans ppart[NPB4] ----

__global__ __launch_bounds__(256) void scan_b(int* __restrict__ part,
                                              int* __restrict__ ppart,
                                              int* __restrict__ S) {
    __shared__ int wsum[4];
    int t = threadIdx.x, lane = t & 63, w = t >> 6;
    if (blockIdx.x == 0) {
        int v = (t < NSB) ? part[t] : 0;
        int incl = v;
        #pragma unroll
        for (int off = 1; off < 64; off <<= 1) {
            int u = __shfl_up(incl, off, 64);
            if (lane >= off) incl += u;
        }
        if (lane == 63) wsum[w] = incl;
        __syncthreads();
        int woff = 0;
        for (int k = 0; k < w; k++) woff += wsum[k];
        if (t < NSB) part[t] = woff + incl - v;
    } else {
        int carry = 0;
        for (int base = 0; base < NPB4; base += 256) {
            int i = base + t;
            int v = (i < NPB4) ? ppart[i] : 0;
            int incl = v;
            #pragma unroll
            for (int off = 1; off < 64; off <<= 1) {
                int u = __shfl_up(incl, off, 64);
                if (lane >= off) incl += u;
            }
            if (lane == 63) wsum[w] = incl;
            __syncthreads();
            int woff = 0;
            for (int k = 0; k < w; k++) woff += wsum[k];
            if (i < NPB4) ppart[i] = carry + woff + incl - v;
            carry += wsum[0] + wsum[1] + wsum[2] + wsum[3];
            __syncthreads();
        }
        if (t == 0) S[NP] = carry;
    }
}

// ---- scan stage C: dst-bin add+cursor | pair add+compact (4 elem/thread) ----

__global__ __launch_bounds__(256) void scan_c(int* __restrict__ offs,
                                              const int* __restrict__ part,
                                              int* __restrict__ cursor,
                                              const int* __restrict__ deg,
                                              int* __restrict__ S,
                                              const int* __restrict__ ppart,
                                              int* __restrict__ pair_src) {
    int b = blockIdx.x, t = threadIdx.x;
    if (b < NSB) {
        int i = b * 256 + t;
        if (i < NBINS) {
            int v = offs[i] + part[i >> 8];
            offs[i] = v;
            cursor[i] = v;
        }
        if (i == 0) offs[NBINS] = E_AUG;
    } else {
        int pb = b - NSB;
        int i0 = pb * 1024 + t * 4;
        if (i0 >= NP) return;
        int pp = ppart[pb];
        int r = i0 / N_NODES;
        int xx = i0 - r * N_NODES;
        const int* dp = deg + pair_rel(r) * N_NODES + xx;
        if (i0 + 3 < NP) {
            int4 sv = *(int4*)(S + i0);
            sv.x += pp; sv.y += pp; sv.z += pp; sv.w += pp;
            *(int4*)(S + i0) = sv;
            int4 d = *(const int4*)dp;
            if (d.x > 0) pair_src[sv.x] = xx;
            if (d.y > 0) pair_src[sv.y] = xx + 1;
            if (d.z > 0) pair_src[sv.z] = xx + 2;
            if (d.w > 0) pair_src[sv.w] = xx + 3;
        } else {
            for (int k = 0; k < 4; k++) {
                int i = i0 + k;
                if (i >= NP) break;
                int s = S[i] + pp;
                S[i] = s;
                if (dp[k] > 0) pair_src[s] = xx + k;
            }
        }
    }
}

// ---------------- fused [block-table | edge scatter] ----------------

__global__ __launch_bounds__(256) void scatter_blk(const int* __restrict__ g,
                                                   const int* __restrict__ deg,
                                                   const int* __restrict__ S,
                                                   int* __restrict__ cursor,
                                                   uint2* __restrict__ sorted,
                                                   int* __restrict__ rowbase,
                                                   int* __restrict__ rowcnt,
                                                   int* __restrict__ blkoffs) {
    int b = blockIdx.x, t = threadIdx.x;
    if (b == 0) {
        __shared__ int wsum[4];
        int lane = t & 63, w = t >> 6;
        int nb = 0;
        if (t < R_AUG) {
            int base = S[t * N_NODES];
            int nxt  = S[(t + 1) * N_NODES];     /* t==100 -> S[NP] = total */
            rowbase[t] = base;
            rowcnt[t]  = nxt - base;
            nb = (nxt - base + BSPAN - 1) / BSPAN;
        }
        int incl = nb;
        #pragma unroll
        for (int off = 1; off < 64; off <<= 1) {
            int u = __shfl_up(incl, off, 64);
            if (lane >= off) incl += u;
        }
        if (lane == 63) wsum[w] = incl;
        __syncthreads();
        int woff = 0;
        for (int k = 0; k < w; k++) woff += wsum[k];
        if (t < R_AUG) blkoffs[t] = woff + incl - nb;
        if (t == R_AUG) blkoffs[R_AUG] = woff + incl;   /* total blocks */
        return;
    }
    int e = (b - 1) * 256 + t;
    if (e >= E_AUG) return;
    int src, rel, dst;
    decode_edge(g, e, src, rel, dst);
    int pos = atomicAdd(&cursor[dst], 1);
    int dg = deg[rel * N_NODES + dst];          // >= 1 by construction
    uint2 rec;
    rec.x = (unsigned)S[rel * N_NODES + src];   // compact Z row
    rec.y = f2u(1.0f / (float)dg);
    sorted[pos] = rec;
}

// ---------------- compact GEMM: Zc[row][o] = xb[pair_src[row]][:] @ W[rel(row)][:][o] ----------------
// Fixed grid; block -> (rel, 512-row span) via binary search in blkoffs.
// Wave w: cols (w&1)*64..+64, tile parity w>>1 (16 tiles of 16 rows each).
// 16 tile indices preloaded; next-tile A prefetch; 4 A-loads : 16 MFMA.
// W rows permuted at load so lane (lr,lq) holds cols no+lq*8+{0..7} of its row.
// XCD swizzle (T1, m204 bijective with runtime total): blocks are rel-major, so
// giving each XCD a CONTIGUOUS logical range co-locates same-rel blocks per XCD
// -> W[r] fetched by ~1 XCD instead of 8 (FETCH 37.7 -> ~24 MB predicted).
// Applied AFTER the early-exit so useful blocks stay balanced across XCDs.

__global__ __launch_bounds__(256, 4) void gemm_compact(const unsigned short* __restrict__ xb,
                                                       const unsigned short* __restrict__ Wt,
                                                       const int* __restrict__ pair_src,
                                                       const int* __restrict__ rowbase,
                                                       const int* __restrict__ rowcnt,
                                                       const int* __restrict__ blkoffs,
                                                       unsigned short* __restrict__ Zc) {
    int b = blockIdx.x;
    int total = blkoffs[R_AUG];
    if (b >= total) return;
    {   // bijective XCD swizzle (m204): hw id -> logical id, xcd gets contiguous chunk
        int q = total >> 3, rr = total & 7;
        int xcd = b & 7, idx = b >> 3;
        b = (xcd < rr ? xcd * (q + 1) : rr * (q + 1) + (xcd - rr) * q) + idx;
    }
    int lo = 0, hi = R_AUG;
    while (hi - lo > 1) {
        int mid = (lo + hi) >> 1;
        if (blkoffs[mid] <= b) lo = mid; else hi = mid;
    }
    int r = lo;
    int lb = b - blkoffs[r];
    int rbase = rowbase[r] + lb * BSPAN;
    int nrows = rowcnt[r] - lb * BSPAN; if (nrows > BSPAN) nrows = BSPAN;

    int t = threadIdx.x, wave = t >> 6, lane = t & 63;
    int lr = lane & 15, lq = lane >> 4;
    int no = (wave & 1) * 64;
    int tp = wave >> 1;
    const unsigned short* Wr = Wt + (size_t)r * D * D;

    // preload all 16 tile indices (independent loads)
    int srcs[16];
    #pragma unroll
    for (int i = 0; i < 16; i++) {
        int row = (tp + 2 * i) * 16 + lr;
        srcs[i] = pair_src[rbase + (row < nrows ? row : 0)];
    }

    int prow = ((lr >> 2) << 3) + (lr & 3);
    bf16x8 w0[4], w1[4], w2[4], w3[4];
    #pragma unroll
    for (int ks = 0; ks < 4; ks++) {
        size_t kb = ks * 32 + lq * 8;
        w0[ks] = *(const bf16x8*)(Wr + (size_t)(no + prow) * D + kb);
        w1[ks] = *(const bf16x8*)(Wr + (size_t)(no + prow + 4) * D + kb);
        w2[ks] = *(const bf16x8*)(Wr + (size_t)(no + 32 + prow) * D + kb);
        w3[ks] = *(const bf16x8*)(Wr + (size_t)(no + 32 + prow + 4) * D + kb);
    }

    bf16x8 a[4];
    {
        const unsigned short* x0 = xb + (size_t)srcs[0] * D + lq * 8;
        #pragma unroll
        for (int ks = 0; ks < 4; ks++) a[ks] = *(const bf16x8*)(x0 + ks * 32);
    }

    #pragma unroll
    for (int i = 0; i < 16; i++) {
        int tile = tp + 2 * i;
        if (tile * 16 >= nrows) break;                  // wave-uniform

        bf16x8 an[4];                                   // prefetch next tile's A
        {
            int ni = (i < 15) ? i + 1 : 15;
            const unsigned short* xn = xb + (size_t)srcs[ni] * D + lq * 8;
            #pragma unroll
            for (int ks = 0; ks < 4; ks++) an[ks] = *(const bf16x8*)(xn + ks * 32);
        }

        f32x4 c0 = {}, c1 = {}, c2 = {}, c3 = {};
        #pragma unroll
        for (int ks = 0; ks < 4; ks++) {
            c0 = __builtin_amdgcn_mfma_f32_16x16x32_bf16(w0[ks], a[ks], c0, 0, 0, 0);
            c1 = __builtin_amdgcn_mfma_f32_16x16x32_bf16(w1[ks], a[ks], c1, 0, 0, 0);
            c2 = __builtin_amdgcn_mfma_f32_16x16x32_bf16(w2[ks], a[ks], c2, 0, 0, 0);
            c3 = __builtin_amdgcn_mfma_f32_16x16x32_bf16(w3[ks], a[ks], c3, 0, 0, 0);
        }
        int row = tile * 16 + lr;
        if (row < nrows) {
            unsigned short* zrow = Zc + ((size_t)(rbase + row) << 7);
            uint4 p0, p1;
            p0.x = (unsigned)f2bf(c0[0]) | ((unsigned)f2bf(c0[1]) << 16);
            p0.y = (unsigned)f2bf(c0[2]) | ((unsigned)f2bf(c0[3]) << 16);
            p0.z = (unsigned)f2bf(c1[0]) | ((unsigned)f2bf(c1[1]) << 16);
            p0.w = (unsigned)f2bf(c1[2]) | ((unsigned)f2bf(c1[3]) << 16);
            p1.x = (unsigned)f2bf(c2[0]) | ((unsigned)f2bf(c2[1]) << 16);
            p1.y = (unsigned)f2bf(c2[2]) | ((unsigned)f2bf(c2[3]) << 16);
            p1.z = (unsigned)f2bf(c3[0]) | ((unsigned)f2bf(c3[1]) << 16);
            p1.w = (unsigned)f2bf(c3[2]) | ((unsigned)f2bf(c3[3]) << 16);
            *(uint4*)(zrow + no + lq * 8) = p0;
            *(uint4*)(zrow + no + 32 + lq * 8) = p1;
        }
        #pragma unroll
        for (int ks = 0; ks < 4; ks++) a[ks] = an[ks];
    }
}

// ---------------- aggregation: one wave per dst, 8 edges in flight ----------------

__global__ __launch_bounds__(256) void agg_pass(const uint2* __restrict__ sorted,
                                                const int* __restrict__ offs,
                                                const unsigned short* __restrict__ Zc,
                                                const float* __restrict__ bias,
                                                float* __restrict__ hf,
                                                unsigned short* __restrict__ hb,
                                                int dorelu) {
    int w = threadIdx.x >> 6, lane = threadIdx.x & 63;
    int dst = blockIdx.x * 4 + w;
    if (dst >= N_NODES) return;
    int e0 = offs[dst], e1 = offs[dst + 1];
    int g = lane >> 3, s = lane & 7;
    float acc[16] = {};

    for (int base = e0; base < e1; base += 64) {
        int n = e1 - base; if (n > 64) n = 64;
        uint2 rec = {0u, 0u};
        if (lane < n) rec = sorted[base + lane];
        int iters = (n + 7) >> 3;
        #pragma unroll 2
        for (int j = 0; j < iters; j++) {
            int ej = j * 8 + g;
            int ec = (ej < n) ? ej : (n - 1);
            unsigned zi = (unsigned)__shfl((int)rec.x, ec, 64);
            unsigned nb = (unsigned)__shfl((int)rec.y, ec, 64);
            float nrm = (ej < n) ? u2f(nb) : 0.0f;
            const unsigned short* zp = Zc + ((size_t)zi << 7) + s * 16;
            uint4 z0 = *(const uint4*)zp;
            uint4 z1 = *(const uint4*)(zp + 8);
            acc[0]  += nrm * bf2f((unsigned short)(z0.x & 0xFFFFu));
            acc[1]  += nrm * bf2f((unsigned short)(z0.x >> 16));
            acc[2]  += nrm * bf2f((unsigned short)(z0.y & 0xFFFFu));
            acc[3]  += nrm * bf2f((unsigned short)(z0.y >> 16));
            acc[4]  += nrm * bf2f((unsigned short)(z0.z & 0xFFFFu));
            acc[5]  += nrm * bf2f((unsigned short)(z0.z >> 16));
            acc[6]  += nrm * bf2f((unsigned short)(z0.w & 0xFFFFu));
            acc[7]  += nrm * bf2f((unsigned short)(z0.w >> 16));
            acc[8]  += nrm * bf2f((unsigned short)(z1.x & 0xFFFFu));
            acc[9]  += nrm * bf2f((unsigned short)(z1.x >> 16));
            acc[10] += nrm * bf2f((unsigned short)(z1.y & 0xFFFFu));
            acc[11] += nrm * bf2f((unsigned short)(z1.y >> 16));
            acc[12] += nrm * bf2f((unsigned short)(z1.z & 0xFFFFu));
            acc[13] += nrm * bf2f((unsigned short)(z1.z >> 16));
            acc[14] += nrm * bf2f((unsigned short)(z1.w & 0xFFFFu));
            acc[15] += nrm * bf2f((unsigned short)(z1.w >> 16));
        }
    }
    #pragma unroll
    for (int k = 0; k < 16; k++) {
        acc[k] += __shfl_down(acc[k], 8, 64);
        acc[k] += __shfl_down(acc[k], 16, 64);
        acc[k] += __shfl_down(acc[k], 32, 64);
    }
    if (g == 0) {
        const float* bp = bias + s * 16;
        float vv[16];
        #pragma unroll
        for (int k = 0; k < 16; k++) vv[k] = bp[k] + acc[k];
        if (dorelu) {
            unsigned short* hp = hb + ((size_t)dst << 7) + s * 16;
            uint4 p0, p1;
            p0.x = (unsigned)f2bf(fmaxf(vv[0], 0.0f))  | ((unsigned)f2bf(fmaxf(vv[1], 0.0f))  << 16);
            p0.y = (unsigned)f2bf(fmaxf(vv[2], 0.0f))  | ((unsigned)f2bf(fmaxf(vv[3], 0.0f))  << 16);
            p0.z = (unsigned)f2bf(fmaxf(vv[4], 0.0f))  | ((unsigned)f2bf(fmaxf(vv[5], 0.0f))  << 16);
            p0.w = (unsigned)f2bf(fmaxf(vv[6], 0.0f))  | ((unsigned)f2bf(fmaxf(vv[7], 0.0f))  << 16);
            p1.x = (unsigned)f2bf(fmaxf(vv[8], 0.0f))  | ((unsigned)f2bf(fmaxf(vv[9], 0.0f))  << 16);
            p1.y = (unsigned)f2bf(fmaxf(vv[10], 0.0f)) | ((unsigned)f2bf(fmaxf(vv[11], 0.0f)) << 16);
            p1.z = (unsigned)f2bf(fmaxf(vv[12], 0.0f)) | ((unsigned)f2bf(fmaxf(vv[13], 0.0f)) << 16);
            p1.w = (unsigned)f2bf(fmaxf(vv[14], 0.0f)) | ((unsigned)f2bf(fmaxf(vv[15], 0.0f)) << 16);
            *(uint4*)hp = p0;
            *(uint4*)(hp + 8) = p1;
        } else {
            float* hp = hf + ((size_t)dst << 7) + s * 16;
            #pragma unroll
            for (int q = 0; q < 4; q++) {
                float4 o = {vv[q * 4], vv[q * 4 + 1], vv[q * 4 + 2], vv[q * 4 + 3]};
                *(float4*)(hp + q * 4) = o;
            }
        }
    }
}

// ---------------- scoring: 4 items/wave (16 lanes x 2 float4 each) ----------------

__global__ __launch_bounds__(256) void score_kernel(const int* __restrict__ batch,
                                                    const float* __restrict__ h2,
                                                    const float* __restrict__ rels,
                                                    float* __restrict__ out) {
    int t = threadIdx.x;
    int wv = t >> 6, q = (t & 63) >> 4, sl = t & 15;
    int i = blockIdx.x * 16 + wv * 4 + q;     // grid 4096 covers 65536 exactly
    int bs = batch[3*i], bp = batch[3*i+1], bo = batch[3*i+2];
    const float* sp = h2   + (size_t)bs * D + sl * 8;
    const float* pp = rels + (size_t)bp * D + sl * 8;
    const float* op = h2   + (size_t)bo * D + sl * 8;
    float4 s0 = *(const float4*)sp,      s1 = *(const float4*)(sp + 4);
    float4 p0 = *(const float4*)pp,      p1 = *(const float4*)(pp + 4);
    float4 o0 = *(const float4*)op,      o1 = *(const float4*)(op + 4);
    float v = s0.x * p0.x * o0.x + s0.y * p0.y * o0.y + s0.z * p0.z * o0.z + s0.w * p0.w * o0.w
            + s1.x * p1.x * o1.x + s1.y * p1.y * o1.y + s1.z * p1.z * o1.z + s1.w * p1.w * o1.w;
    #pragma unroll
    for (int off = 8; off > 0; off >>= 1) v += __shfl_down(v, off, 16);
    if (sl == 0) out[i] = v;
}

// ---------------- host ----------------

extern "C" void kernel_launch(void* const* d_in, const int* in_sizes, int n_in,
                              void* d_out, int out_size, void* d_ws, size_t ws_size,
                              hipStream_t stream) {
    const int*   graph = (const int*)  d_in[0];
    const int*   batch = (const int*)  d_in[1];
    const float* emb   = (const float*)d_in[2];
    const float* W1    = (const float*)d_in[3];
    const float* b1    = (const float*)d_in[4];
    const float* W2    = (const float*)d_in[5];
    const float* b2    = (const float*)d_in[6];
    const float* rels  = (const float*)d_in[7];
    float* out = (float*)d_out;

    char* base = (char*)d_ws;
    size_t off = 0;
    auto take = [&](size_t bytes) -> char* {
        char* q = base + off;
        off += (bytes + 255) & ~(size_t)255;
        return q;
    };
    int*            deg     = (int*)           take((size_t)NP * 4);
    int*            S       = (int*)           take((size_t)(NP + 1) * 4);
    int*            pair_src= (int*)           take((size_t)E_AUG * 4);
    int*            ppart   = (int*)           take((size_t)NPB4 * 4);
    int*            rowbase = (int*)           take((size_t)(R_AUG + 1) * 4);
    int*            rowcnt  = (int*)           take((size_t)(R_AUG + 1) * 4);
    int*            blkoffs = (int*)           take((size_t)(R_AUG + 2) * 4);
    unsigned short* xb      = (unsigned short*)take((size_t)N_NODES * D * 2);
    float*          h2      = (float*)         take((size_t)N_NODES * D * 4);
    unsigned short* h1b     = (unsigned short*)take((size_t)N_NODES * D * 2);
    unsigned short* W1t     = (unsigned short*)take((size_t)R_AUG * D * D * 2);
    unsigned short* W2t     = (unsigned short*)take((size_t)R_AUG * D * D * 2);
    int*            offs    = (int*)           take((size_t)(NBINS + 1) * 4);
    int*            cursor  = (int*)           take((size_t)NBINS * 4);
    int*            part    = (int*)           take((size_t)NSB * 4);
    uint2*          sorted  = (uint2*)         take((size_t)E_AUG * 8);
    unsigned short* Zc      = (unsigned short*)take((size_t)E_AUG * D * 2);  // worst-case 166 MB

    hipMemsetAsync(deg, 0, (size_t)NP * 4, stream);
    prep_all<<<dim3(HIST_BLOCKS + TW_BLOCKS + PREPX_BLOCKS), 256, 0, stream>>>(
        emb, xb, W1, W2, W1t, W2t, graph, deg);
    scan_a<<<dim3(NSB + NPB4), 256, 0, stream>>>(deg, offs, part, S, ppart);
    scan_b<<<dim3(2), 256, 0, stream>>>(part, ppart, S);
    scan_c<<<dim3(NSB + NPB4), 256, 0, stream>>>(offs, part, cursor, deg, S, ppart, pair_src);
    scatter_blk<<<dim3(1 + SCAT_BLOCKS), 256, 0, stream>>>(
        graph, deg, S, cursor, sorted, rowbase, rowcnt, blkoffs);

    gemm_compact<<<dim3(GEMM_NBLK), 256, 0, stream>>>(xb, W1t, pair_src, rowbase, rowcnt, blkoffs, Zc);
    agg_pass<<<dim3((N_NODES + 3) / 4), 256, 0, stream>>>(sorted, offs, Zc, b1, (float*)0, h1b, 1);
    gemm_compact<<<dim3(GEMM_NBLK), 256, 0, stream>>>(h1b, W2t, pair_src, rowbase, rowcnt, blkoffs, Zc);
    agg_pass<<<dim3((N_NODES + 3) / 4), 256, 0, stream>>>(sorted, offs, Zc, b2, h2, (unsigned short*)0, 0);
    score_kernel<<<dim3(N_BATCH / 16), 256, 0, stream>>>(batch, h2, rels, out);
}